// Round 4
// baseline (4578.317 us; speedup 1.0000x reference)
//
#include <hip/hip_runtime.h>
#include <hip/hip_bf16.h>
#include <cstdint>

#define B_ 32
#define T_ 1024
#define E_ 256
#define H_ 256
#define G_ 1024
#define NTAG 14

typedef __bf16 bf8_t __attribute__((ext_vector_type(8)));
typedef float f4_t __attribute__((ext_vector_type(4)));
typedef int i4_t __attribute__((ext_vector_type(4)));
typedef unsigned short u16x4 __attribute__((ext_vector_type(4)));

__device__ __forceinline__ unsigned short f2bf(float f) {
    unsigned u = __builtin_bit_cast(unsigned, f);
    u = u + 0x7FFFu + ((u >> 16) & 1u);
    return (unsigned short)(u >> 16);
}
__device__ __forceinline__ float bf2f(unsigned short s) {
    unsigned u = ((unsigned)s) << 16;
    return __builtin_bit_cast(float, u);
}
__device__ __forceinline__ float sigf(float x) { return 1.0f / (1.0f + __expf(-x)); }
// branch-free tanh: overflow-safe (exp->inf => 1; exp->0 => -1)
__device__ __forceinline__ float tanh2_(float x) {
    float e = __expf(2.0f * x);
    return 1.0f - 2.0f / (e + 1.0f);
}
__device__ __forceinline__ f4_t mfma16(bf8_t a, bf8_t b, f4_t c) {
    return __builtin_amdgcn_mfma_f32_16x16x32_bf16(a, b, c, 0, 0, 0);
}

// ---------------- prep: wih->bf16, combine biases, wout pad ----------------
__global__ __launch_bounds__(256) void prep_kernel(
        const float* wih_f, const float* wih_b,
        const float* bih_f, const float* bhh_f,
        const float* bih_b, const float* bhh_b,
        const float* wout,
        unsigned short* wih_bf, float* biasc, unsigned short* wout_bf) {
    int tid = blockIdx.x * 256 + threadIdx.x;
    if (tid < 524288) {                       // 2 x 262144: [d][1024][256]
        int d = tid >> 18, off = tid & 262143;
        wih_bf[tid] = f2bf((d ? wih_b : wih_f)[off]);
        return;
    }
    int t2 = tid - 524288;
    if (t2 < 8192) {                          // wout padded [16][512]
        int n = t2 >> 9, k = t2 & 511;
        wout_bf[t2] = (n < NTAG) ? f2bf(wout[n * 512 + k]) : (unsigned short)0;
        return;
    }
    int t3 = t2 - 8192;
    if (t3 < 2048) {                          // biasc [2][1024]
        int d = t3 >> 10, g = t3 & 1023;
        biasc[t3] = d ? (bih_b[g] + bhh_b[g]) : (bih_f[g] + bhh_f[g]);
    }
}

// ---------------- whh -> int8 with per-row scale ----------------
__global__ __launch_bounds__(256) void wquant_kernel(const float* whh_f, const float* whh_b,
                                                     signed char* qw, float* sw) {
    int row = blockIdx.x * 4 + (threadIdx.x >> 6);   // 0..2047 = [d][1024]
    int l = threadIdx.x & 63;
    int d = row >> 10, rr = row & 1023;
    const float* src = (d ? whh_b : whh_f) + (size_t)rr * 256;
    float4 v = *reinterpret_cast<const float4*>(src + 4 * l);
    float am = fmaxf(fmaxf(fabsf(v.x), fabsf(v.y)), fmaxf(fabsf(v.z), fabsf(v.w)));
#pragma unroll
    for (int off = 1; off < 64; off <<= 1)
        am = fmaxf(am, __shfl_xor(am, off));
    am = fmaxf(am, 1e-20f);
    float inv = 127.f / am;
    int q0 = (int)__builtin_rintf(v.x * inv), q1 = (int)__builtin_rintf(v.y * inv);
    int q2 = (int)__builtin_rintf(v.z * inv), q3 = (int)__builtin_rintf(v.w * inv);
    unsigned u = (q0 & 255) | ((q1 & 255) << 8) | ((q2 & 255) << 16) | ((q3 & 255) << 24);
    *reinterpret_cast<unsigned*>(qw + (size_t)row * 256 + 4 * l) = u;
    if (l == 0) sw[row] = am / 127.f;
}

// ---------------- embedding gather -> bf16 ----------------
__global__ __launch_bounds__(256) void embed_kernel(const int* sent, const float* emb,
                                                    unsigned short* xbf) {
    int tid = blockIdx.x * 256 + threadIdx.x; // 32768*64 threads
    int bt = tid >> 6;
    int e0 = (tid & 63) << 2;
    int tok = sent[bt];
    float4 v = *reinterpret_cast<const float4*>(emb + (size_t)tok * E_ + e0);
    u16x4 o;
    o[0] = f2bf(v.x); o[1] = f2bf(v.y); o[2] = f2bf(v.z); o[3] = f2bf(v.w);
    *reinterpret_cast<u16x4*>(xbf + (size_t)bt * E_ + e0) = o;
}

// ---------------- input projection -> xg2[d][bh][t][n][16 mloc] ----------------
__global__ __launch_bounds__(256) void xproj_kernel(const unsigned short* xbf,
        const unsigned short* wih_bf, const float* biasc, unsigned short* xg2) {
    int mt = blockIdx.x;                 // 0..2047 (16 tokens each)
    int d = blockIdx.y >> 2;
    int ns = blockIdx.y & 3;             // 256-wide n slice
    int w = threadIdx.x >> 6, l = threadIdx.x & 63;
    int l15 = l & 15, lgp = l >> 4;

    bf8_t a[8];
    const unsigned short* arow = xbf + (size_t)(16 * mt + l15) * E_ + 8 * lgp;
#pragma unroll
    for (int ks = 0; ks < 8; ++ks)
        a[ks] = *reinterpret_cast<const bf8_t*>(arow + 32 * ks);

    int nbase = ns * 256 + w * 64;
    const unsigned short* wd = wih_bf + (size_t)d * 262144;
    f4_t acc[4];
#pragma unroll
    for (int p = 0; p < 4; ++p) { acc[p][0] = 0.f; acc[p][1] = 0.f; acc[p][2] = 0.f; acc[p][3] = 0.f; }
#pragma unroll
    for (int p = 0; p < 4; ++p) {
        int n = nbase + 16 * p + l15;
        const unsigned short* brow = wd + (size_t)n * E_ + 8 * lgp;
#pragma unroll
        for (int ks = 0; ks < 8; ++ks) {
            bf8_t b = *reinterpret_cast<const bf8_t*>(brow + 32 * ks);
            acc[p] = mfma16(a[ks], b, acc[p]);
        }
    }
#pragma unroll
    for (int p = 0; p < 4; ++p) {
        int n = nbase + 16 * p + l15;
        float bias = biasc[d * G_ + n];
#pragma unroll
        for (int r = 0; r < 4; ++r) {
            int bt = 16 * mt + 4 * lgp + r;
            int b = bt >> 10, tt = bt & 1023;
            xg2[(((size_t)(d * 2 + (b >> 4)) * 1024 + tt) * 1024 + n) * 16 + (b & 15)]
                = f2bf(acc[p][r] + bias);
        }
    }
}

// ---------------- recurrence: 4 independent WGs = (dir, batch-16), i8 weights in regs ----
__global__ __launch_bounds__(512, 2) void lstm_kernel(const unsigned short* xg2,
        const signed char* qw, const float* sw, const float* h0, const float* c0,
        unsigned short* hs) {
    int bid = blockIdx.x;            // 0..3
    int bh = bid & 1, d = bid >> 1;
    int tid = threadIdx.x;
    int w = tid >> 6, l = tid & 63, l15 = l & 15, lgp = l >> 4;

    __shared__ __attribute__((aligned(16))) signed char h8[2][16][272];
    __shared__ float red_sh[8];

    // resident int8 weights: wave w owns j-cols [32w,32w+32), all 4 gate types
    const signed char* qwd = qw + (size_t)d * 262144;
    i4_t wreg[4][2][4];
    float swl[4][2];
#pragma unroll
    for (int gt = 0; gt < 4; ++gt)
#pragma unroll
        for (int jt = 0; jt < 2; ++jt) {
            int n = 256 * gt + 32 * w + 16 * jt + l15;
            swl[gt][jt] = sw[d * 1024 + n];
#pragma unroll
            for (int ks = 0; ks < 4; ++ks)
                wreg[gt][jt][ks] = *reinterpret_cast<const i4_t*>(
                    qwd + (size_t)n * 256 + 64 * ks + 16 * lgp);
        }
#pragma unroll
    for (int gt = 0; gt < 4; ++gt)
#pragma unroll
        for (int jt = 0; jt < 2; ++jt)
#pragma unroll
            for (int ks = 0; ks < 4; ++ks)
                asm volatile("" : "+v"(wreg[gt][jt][ks]));   // pin: keep resident

    // c init
    float c[2][4];
#pragma unroll
    for (int jt = 0; jt < 2; ++jt)
#pragma unroll
        for (int r = 0; r < 4; ++r)
            c[jt][r] = c0[((size_t)d * 32 + 16 * bh + 4 * lgp + r) * 256 + 32 * w + 16 * jt + l15];

    // h0: block amax -> per-step-0 scale, quantize into parity-1
    float v0[8]; float am = 0.f;
#pragma unroll
    for (int k = 0; k < 8; ++k) {
        int e = tid * 8 + k;  // 0..4095
        int m = e >> 8, col = e & 255;
        v0[k] = h0[((size_t)d * 32 + 16 * bh + m) * 256 + col];
        am = fmaxf(am, fabsf(v0[k]));
    }
#pragma unroll
    for (int off = 1; off < 64; off <<= 1)
        am = fmaxf(am, __shfl_xor(am, off));
    if (l == 0) red_sh[w] = am;
    __syncthreads();
    float bmax = red_sh[0];
#pragma unroll
    for (int q = 1; q < 8; ++q) bmax = fmaxf(bmax, red_sh[q]);
    bmax = fmaxf(bmax, 1e-20f);
    float s0 = bmax / 127.f;
    float inv_s0 = 127.f / bmax;
#pragma unroll
    for (int k = 0; k < 8; ++k) {
        int e = tid * 8 + k;
        int m = e >> 8, col = e & 255;
        h8[1][m][col] = (signed char)(int)__builtin_rintf(v0[k] * inv_s0);
    }
    asm volatile("s_waitcnt lgkmcnt(0)" ::: "memory");
    __builtin_amdgcn_sched_barrier(0);
    __builtin_amdgcn_s_barrier();

    const unsigned short* xbase = xg2 + (size_t)(d * 2 + bh) * 1024 * 16384;
    float dq[4][2];
#pragma unroll
    for (int gt = 0; gt < 4; ++gt)
#pragma unroll
        for (int jt = 0; jt < 2; ++jt) dq[gt][jt] = swl[gt][jt] * s0;

    for (int s = 0; s < 1024; ++s) {
        int t = d ? (1023 - s) : s;
        int rp = (s + 1) & 1, wp = s & 1;

        // gate pre-activations from xg2 (coalesced u16x4; in flight under MFMA)
        u16x4 xv[4][2];
        const unsigned short* xt = xbase + (size_t)t * 16384;
#pragma unroll
        for (int gt = 0; gt < 4; ++gt)
#pragma unroll
            for (int jt = 0; jt < 2; ++jt) {
                int n = 256 * gt + 32 * w + 16 * jt + l15;
                xv[gt][jt] = *reinterpret_cast<const u16x4*>(xt + n * 16 + 4 * lgp);
            }

        i4_t acc[4][2];
#pragma unroll
        for (int gt = 0; gt < 4; ++gt)
#pragma unroll
            for (int jt = 0; jt < 2; ++jt) acc[gt][jt] = (i4_t){0, 0, 0, 0};

#pragma unroll
        for (int ks = 0; ks < 4; ++ks) {
            i4_t a = *reinterpret_cast<const i4_t*>(&h8[rp][l15][64 * ks + 16 * lgp]);
#pragma unroll
            for (int gt = 0; gt < 4; ++gt)
#pragma unroll
                for (int jt = 0; jt < 2; ++jt)
                    acc[gt][jt] = __builtin_amdgcn_mfma_i32_16x16x64_i8(
                        a, wreg[gt][jt][ks], acc[gt][jt], 0, 0, 0);
        }

        // gates + state update (VALU phase)
#pragma unroll
        for (int jt = 0; jt < 2; ++jt) {
            int j = 32 * w + 16 * jt + l15;
#pragma unroll
            for (int r = 0; r < 4; ++r) {
                float pi = dq[0][jt] * (float)acc[0][jt][r] + bf2f(xv[0][jt][r]);
                float pf = dq[1][jt] * (float)acc[1][jt][r] + bf2f(xv[1][jt][r]);
                float pg = dq[2][jt] * (float)acc[2][jt][r] + bf2f(xv[2][jt][r]);
                float po = dq[3][jt] * (float)acc[3][jt][r] + bf2f(xv[3][jt][r]);
                float iv = sigf(pi), fv = sigf(pf), ov = sigf(po);
                float gv = tanh2_(pg);
                float cn = fv * c[jt][r] + iv * gv;
                c[jt][r] = cn;
                float hv = ov * tanh2_(cn);
                int m = 4 * lgp + r;
                hs[((size_t)(16 * bh + m) * 1024 + t) * 512 + d * 256 + j] = f2bf(hv);
                h8[wp][m][j] = (signed char)(int)__builtin_rintf(hv * 127.f);
            }
        }
        if (s == 0) {
#pragma unroll
            for (int gt = 0; gt < 4; ++gt)
#pragma unroll
                for (int jt = 0; jt < 2; ++jt) dq[gt][jt] = swl[gt][jt] * (1.f / 127.f);
        }
        // barrier: drain LDS only (hs stores + next xv loads stay in flight)
        asm volatile("s_waitcnt lgkmcnt(0)" ::: "memory");
        __builtin_amdgcn_sched_barrier(0);
        __builtin_amdgcn_s_barrier();
    }
}

// ---------------- logits = hs @ Wout^T + b_out (N padded to 16) ----------------
__global__ __launch_bounds__(256) void logits_kernel(const unsigned short* hs,
        const unsigned short* wout_bf, const float* b_out, float* logits) {
    int w = threadIdx.x >> 6, l = threadIdx.x & 63, l15 = l & 15, lgp = l >> 4;
    int mt = blockIdx.x * 4 + w;         // 0..2047
    const unsigned short* arow = hs + (size_t)(16 * mt + l15) * 512 + 8 * lgp;
    const unsigned short* brow = wout_bf + (size_t)l15 * 512 + 8 * lgp;
    f4_t acc; acc[0] = 0.f; acc[1] = 0.f; acc[2] = 0.f; acc[3] = 0.f;
#pragma unroll
    for (int ks = 0; ks < 16; ++ks) {
        bf8_t a = *reinterpret_cast<const bf8_t*>(arow + 32 * ks);
        bf8_t b = *reinterpret_cast<const bf8_t*>(brow + 32 * ks);
        acc = mfma16(a, b, acc);
    }
    float bo = (l15 < NTAG) ? b_out[l15] : 0.0f;
#pragma unroll
    for (int r = 0; r < 4; ++r) {
        int bt = 16 * mt + 4 * lgp + r;
        logits[(size_t)bt * 16 + l15] = acc[r] + bo;
    }
}

// ---------------- Viterbi: one wave per sequence ----------------
__global__ __launch_bounds__(64) void viterbi_kernel(const float* logits, const float* crf,
                                                     float* out) {
    int b = blockIdx.x, j = threadIdx.x;
    __shared__ unsigned char bp[1024][16];
    __shared__ unsigned char pth[1024];
    float crfj[NTAG];
#pragma unroll
    for (int i = 0; i < NTAG; ++i)
        crfj[i] = (j < NTAG) ? crf[i * NTAG + j] : 0.0f;
    const float* lgt = logits + (size_t)b * 1024 * 16;
    float v = (j < NTAG) ? lgt[j] : -3.0e38f;
    for (int t = 1; t < 1024; ++t) {
        float lt = (j < NTAG) ? lgt[t * 16 + j] : 0.0f;
        float best = -3.0e38f; int arg = 0;
#pragma unroll
        for (int i = 0; i < NTAG; ++i) {
            float s = __shfl(v, i) + crfj[i];
            if (s > best) { best = s; arg = i; }   // strict > keeps lowest index (jnp.argmax)
        }
        v = (j < NTAG) ? (lt + best) : -3.0e38f;
        if (j < 16) bp[t][j] = (unsigned char)arg;
    }
    float best = -3.0e38f; int tag = 0;
#pragma unroll
    for (int jj = 0; jj < NTAG; ++jj) {
        float s = __shfl(v, jj);
        if (s > best) { best = s; tag = jj; }
    }
    __syncthreads();
    if (j == 0) {
        out[b] = best;
        int tg = tag;
        pth[1023] = (unsigned char)tg;
        for (int t = 1023; t >= 1; --t) {
            tg = bp[t][tg];
            pth[t - 1] = (unsigned char)tg;
        }
    }
    __syncthreads();
    float* pout = out + 32 + (size_t)b * 1024;
    for (int t = j; t < 1024; t += 64)
        pout[t] = (float)pth[t];
}

extern "C" void kernel_launch(void* const* d_in, const int* in_sizes, int n_in,
                              void* d_out, int out_size, void* d_ws, size_t ws_size,
                              hipStream_t stream) {
    const int* sent = (const int*)d_in[0];
    const float* emb = (const float*)d_in[1];
    const float* wih_f = (const float*)d_in[2];
    const float* whh_f = (const float*)d_in[3];
    const float* bih_f = (const float*)d_in[4];
    const float* bhh_f = (const float*)d_in[5];
    const float* wih_b = (const float*)d_in[6];
    const float* whh_b = (const float*)d_in[7];
    const float* bih_b = (const float*)d_in[8];
    const float* bhh_b = (const float*)d_in[9];
    const float* h0 = (const float*)d_in[10];
    const float* c0 = (const float*)d_in[11];
    const float* wout = (const float*)d_in[12];
    const float* b_out = (const float*)d_in[13];
    const float* crf = (const float*)d_in[14];

    char* ws = (char*)d_ws;
    signed char* qw       = (signed char*)(ws + 0);               // 512 KiB
    float* sw             = (float*)(ws + 524288);                // 8 KiB
    unsigned short* wih_bf = (unsigned short*)(ws + 1048576);     // 1 MiB
    float* biasc          = (float*)(ws + 2097152);               // 8 KiB
    unsigned short* wout_bf = (unsigned short*)(ws + 2105344);    // 16 KiB
    unsigned short* xbf   = (unsigned short*)(ws + 2121728);      // 16 MiB
    unsigned short* xg2   = (unsigned short*)(ws + 18898944);     // 128 MiB
    unsigned short* hs    = (unsigned short*)(ws + 153116672);    // 32 MiB
    float* logits         = (float*)(ws + 186671104);             // 2 MiB
    float* out = (float*)d_out;

    hipLaunchKernelGGL(prep_kernel, dim3(2088), dim3(256), 0, stream,
                       wih_f, wih_b, bih_f, bhh_f, bih_b, bhh_b, wout,
                       wih_bf, biasc, wout_bf);
    hipLaunchKernelGGL(wquant_kernel, dim3(512), dim3(256), 0, stream,
                       whh_f, whh_b, qw, sw);
    hipLaunchKernelGGL(embed_kernel, dim3(8192), dim3(256), 0, stream, sent, emb, xbf);
    hipLaunchKernelGGL(xproj_kernel, dim3(2048, 8), dim3(256), 0, stream,
                       xbf, wih_bf, biasc, xg2);
    hipLaunchKernelGGL(lstm_kernel, dim3(4), dim3(512), 0, stream,
                       xg2, qw, sw, h0, c0, hs);
    hipLaunchKernelGGL(logits_kernel, dim3(512), dim3(256), 0, stream,
                       hs, wout_bf, b_out, logits);
    hipLaunchKernelGGL(viterbi_kernel, dim3(32), dim3(64), 0, stream, logits, crf, out);
}

// Round 5
// 4445.604 us; speedup vs baseline: 1.0299x; 1.0299x over previous
//
#include <hip/hip_runtime.h>
#include <hip/hip_bf16.h>
#include <cstdint>

#define B_ 32
#define T_ 1024
#define E_ 256
#define H_ 256
#define G_ 1024
#define NTAG 14

typedef __bf16 bf8_t __attribute__((ext_vector_type(8)));
typedef float f4_t __attribute__((ext_vector_type(4)));
typedef int i4_t __attribute__((ext_vector_type(4)));
typedef unsigned short u16x4 __attribute__((ext_vector_type(4)));
typedef unsigned short u16x8 __attribute__((ext_vector_type(8)));

__device__ __forceinline__ unsigned short f2bf(float f) {
    unsigned u = __builtin_bit_cast(unsigned, f);
    u = u + 0x7FFFu + ((u >> 16) & 1u);
    return (unsigned short)(u >> 16);
}
__device__ __forceinline__ float bf2f(unsigned short s) {
    unsigned u = ((unsigned)s) << 16;
    return __builtin_bit_cast(float, u);
}
__device__ __forceinline__ float sigf(float x) { return 1.0f / (1.0f + __expf(-x)); }
// branch-free tanh: overflow-safe (exp->inf => 1; exp->0 => -1)
__device__ __forceinline__ float tanh2_(float x) {
    float e = __expf(2.0f * x);
    return 1.0f - 2.0f / (e + 1.0f);
}
__device__ __forceinline__ f4_t mfma16(bf8_t a, bf8_t b, f4_t c) {
    return __builtin_amdgcn_mfma_f32_16x16x32_bf16(a, b, c, 0, 0, 0);
}

// ---------------- prep: wih->bf16, combine biases, wout pad ----------------
__global__ __launch_bounds__(256) void prep_kernel(
        const float* wih_f, const float* wih_b,
        const float* bih_f, const float* bhh_f,
        const float* bih_b, const float* bhh_b,
        const float* wout,
        unsigned short* wih_bf, float* biasc, unsigned short* wout_bf) {
    int tid = blockIdx.x * 256 + threadIdx.x;
    if (tid < 524288) {                       // 2 x 262144: [d][1024][256]
        int d = tid >> 18, off = tid & 262143;
        wih_bf[tid] = f2bf((d ? wih_b : wih_f)[off]);
        return;
    }
    int t2 = tid - 524288;
    if (t2 < 8192) {                          // wout padded [16][512]
        int n = t2 >> 9, k = t2 & 511;
        wout_bf[t2] = (n < NTAG) ? f2bf(wout[n * 512 + k]) : (unsigned short)0;
        return;
    }
    int t3 = t2 - 8192;
    if (t3 < 2048) {                          // biasc [2][1024]
        int d = t3 >> 10, g = t3 & 1023;
        biasc[t3] = d ? (bih_b[g] + bhh_b[g]) : (bih_f[g] + bhh_f[g]);
    }
}

// ---------------- whh -> int8 with per-row scale ----------------
__global__ __launch_bounds__(256) void wquant_kernel(const float* whh_f, const float* whh_b,
                                                     signed char* qw, float* sw) {
    int row = blockIdx.x * 4 + (threadIdx.x >> 6);   // 0..2047 = [d][1024]
    int l = threadIdx.x & 63;
    int d = row >> 10, rr = row & 1023;
    const float* src = (d ? whh_b : whh_f) + (size_t)rr * 256;
    float4 v = *reinterpret_cast<const float4*>(src + 4 * l);
    float am = fmaxf(fmaxf(fabsf(v.x), fabsf(v.y)), fmaxf(fabsf(v.z), fabsf(v.w)));
#pragma unroll
    for (int off = 1; off < 64; off <<= 1)
        am = fmaxf(am, __shfl_xor(am, off));
    am = fmaxf(am, 1e-20f);
    float inv = 127.f / am;
    int q0 = (int)__builtin_rintf(v.x * inv), q1 = (int)__builtin_rintf(v.y * inv);
    int q2 = (int)__builtin_rintf(v.z * inv), q3 = (int)__builtin_rintf(v.w * inv);
    unsigned u = (q0 & 255) | ((q1 & 255) << 8) | ((q2 & 255) << 16) | ((q3 & 255) << 24);
    *reinterpret_cast<unsigned*>(qw + (size_t)row * 256 + 4 * l) = u;
    if (l == 0) sw[row] = am / 127.f;
}

// ---------------- embedding gather -> bf16 ----------------
__global__ __launch_bounds__(256) void embed_kernel(const int* sent, const float* emb,
                                                    unsigned short* xbf) {
    int tid = blockIdx.x * 256 + threadIdx.x; // 32768*64 threads
    int bt = tid >> 6;
    int e0 = (tid & 63) << 2;
    int tok = sent[bt];
    float4 v = *reinterpret_cast<const float4*>(emb + (size_t)tok * E_ + e0);
    u16x4 o;
    o[0] = f2bf(v.x); o[1] = f2bf(v.y); o[2] = f2bf(v.z); o[3] = f2bf(v.w);
    *reinterpret_cast<u16x4*>(xbf + (size_t)bt * E_ + e0) = o;
}

// ---- input projection -> xg2[d][bh][t][n][16 m], coalesced via LDS transpose ----
// block = (t, d*8 + bh*4 + ns): M-tile = 16 batch rows (bh half) at fixed t.
__global__ __launch_bounds__(256) void xproj_kernel(const unsigned short* xbf,
        const unsigned short* wih_bf, const float* biasc, unsigned short* xg2) {
    int t = blockIdx.x;                  // 0..1023
    int y = blockIdx.y;                  // d*8 + bh*4 + ns
    int ns = y & 3, bh = (y >> 2) & 1, d = y >> 3;
    int w = threadIdx.x >> 6, l = threadIdx.x & 63;
    int l15 = l & 15, lgp = l >> 4;
    __shared__ unsigned short sh[256][16];

    bf8_t a[8];
    const unsigned short* arow = xbf + ((size_t)(16 * bh + l15) * 1024 + t) * E_ + 8 * lgp;
#pragma unroll
    for (int ks = 0; ks < 8; ++ks)
        a[ks] = *reinterpret_cast<const bf8_t*>(arow + 32 * ks);

    int nbase = ns * 256 + w * 64;
    const unsigned short* wd = wih_bf + (size_t)d * 262144;
    f4_t acc[4];
#pragma unroll
    for (int p = 0; p < 4; ++p) { acc[p][0] = 0.f; acc[p][1] = 0.f; acc[p][2] = 0.f; acc[p][3] = 0.f; }
#pragma unroll
    for (int p = 0; p < 4; ++p) {
        int n = nbase + 16 * p + l15;
        const unsigned short* brow = wd + (size_t)n * E_ + 8 * lgp;
#pragma unroll
        for (int ks = 0; ks < 8; ++ks) {
            bf8_t b = *reinterpret_cast<const bf8_t*>(brow + 32 * ks);
            acc[p] = mfma16(a[ks], b, acc[p]);
        }
    }
#pragma unroll
    for (int p = 0; p < 4; ++p) {
        int n = nbase + 16 * p + l15;
        float bias = biasc[d * G_ + n];
#pragma unroll
        for (int r = 0; r < 4; ++r)
            sh[w * 64 + 16 * p + l15][4 * lgp + r] = f2bf(acc[p][r] + bias);
    }
    __syncthreads();
    // writeout: thread q owns n_local q -> 32B contiguous
    int q = threadIdx.x;
    unsigned short* dst = xg2 +
        (((size_t)(d * 2 + bh) * 1024 + t) * 1024 + ns * 256 + q) * 16;
    u16x8 v0 = *reinterpret_cast<const u16x8*>(&sh[q][0]);
    u16x8 v1 = *reinterpret_cast<const u16x8*>(&sh[q][8]);
    *reinterpret_cast<u16x8*>(dst) = v0;
    *reinterpret_cast<u16x8*>(dst + 8) = v1;
}

// ---------------- recurrence: 4 independent WGs = (dir, batch-16) ----------------
// i8 weights: jt=0 half in registers (64 VGPR/lane), jt=1 half in LDS (128 KiB).
__global__ __launch_bounds__(512, 2) void lstm_kernel(const unsigned short* xg2,
        const signed char* qw, const float* sw, const float* h0, const float* c0,
        unsigned short* hs) {
    int bid = blockIdx.x;            // 0..3
    int bh = bid & 1, d = bid >> 1;
    int tid = threadIdx.x;
    int w = tid >> 6, l = tid & 63, l15 = l & 15, lgp = l >> 4;

    __shared__ __attribute__((aligned(16))) signed char h8[2][16][272];
    __shared__ i4_t wsh[8192];       // 128 KiB: [(w*4+gt)*4+ks][64 lanes] x 16B
    __shared__ float red_sh[8];

    const signed char* qwd = qw + (size_t)d * 262144;
    float swl[4][2];

    // jt=0 weights -> registers (16 quads = 64 VGPR)
    i4_t wreg[4][4];
#pragma unroll
    for (int gt = 0; gt < 4; ++gt) {
        int n0 = 256 * gt + 32 * w + l15;
        swl[gt][0] = sw[d * 1024 + n0];
        swl[gt][1] = sw[d * 1024 + n0 + 16];
#pragma unroll
        for (int ks = 0; ks < 4; ++ks)
            wreg[gt][ks] = *reinterpret_cast<const i4_t*>(
                qwd + (size_t)n0 * 256 + 64 * ks + 16 * lgp);
    }
#pragma unroll
    for (int gt = 0; gt < 4; ++gt)
#pragma unroll
        for (int ks = 0; ks < 4; ++ks)
            asm volatile("" : "+v"(wreg[gt][ks]));   // keep resident

    // jt=1 weights -> LDS
    int wbase = w * 1024 + l;
#pragma unroll
    for (int gt = 0; gt < 4; ++gt) {
        int n1 = 256 * gt + 32 * w + 16 + l15;
#pragma unroll
        for (int ks = 0; ks < 4; ++ks)
            wsh[wbase + (gt * 4 + ks) * 64] = *reinterpret_cast<const i4_t*>(
                qwd + (size_t)n1 * 256 + 64 * ks + 16 * lgp);
    }

    // c init
    float c[2][4];
#pragma unroll
    for (int jt = 0; jt < 2; ++jt)
#pragma unroll
        for (int r = 0; r < 4; ++r)
            c[jt][r] = c0[((size_t)d * 32 + 16 * bh + 4 * lgp + r) * 256 + 32 * w + 16 * jt + l15];

    // h0: block amax -> step-0 scale, quantize into parity-1
    float v0[8]; float am = 0.f;
#pragma unroll
    for (int k = 0; k < 8; ++k) {
        int e = tid * 8 + k;  // 0..4095
        int m = e >> 8, col = e & 255;
        v0[k] = h0[((size_t)d * 32 + 16 * bh + m) * 256 + col];
        am = fmaxf(am, fabsf(v0[k]));
    }
#pragma unroll
    for (int off = 1; off < 64; off <<= 1)
        am = fmaxf(am, __shfl_xor(am, off));
    if (l == 0) red_sh[w] = am;
    __syncthreads();
    float bmax = red_sh[0];
#pragma unroll
    for (int q = 1; q < 8; ++q) bmax = fmaxf(bmax, red_sh[q]);
    bmax = fmaxf(bmax, 1e-20f);
    float s0 = bmax / 127.f;
    float inv_s0 = 127.f / bmax;
#pragma unroll
    for (int k = 0; k < 8; ++k) {
        int e = tid * 8 + k;
        int m = e >> 8, col = e & 255;
        h8[1][m][col] = (signed char)(int)__builtin_rintf(v0[k] * inv_s0);
    }
    __syncthreads();   // weights staged + h(-1) ready

    const unsigned short* xbase = xg2 + (size_t)(d * 2 + bh) * 1024 * 16384;
    float dq[4][2];
#pragma unroll
    for (int gt = 0; gt < 4; ++gt)
#pragma unroll
        for (int jt = 0; jt < 2; ++jt) dq[gt][jt] = swl[gt][jt] * s0;

    for (int s = 0; s < 1024; ++s) {
        int t = d ? (1023 - s) : s;
        int rp = (s + 1) & 1, wp = s & 1;

        // gate pre-activations (coalesced u16x4; in flight under MFMA)
        u16x4 xv[4][2];
        const unsigned short* xt = xbase + (size_t)t * 16384;
#pragma unroll
        for (int gt = 0; gt < 4; ++gt)
#pragma unroll
            for (int jt = 0; jt < 2; ++jt) {
                int n = 256 * gt + 32 * w + 16 * jt + l15;
                xv[gt][jt] = *reinterpret_cast<const u16x4*>(xt + n * 16 + 4 * lgp);
            }

        i4_t a[4];
#pragma unroll
        for (int ks = 0; ks < 4; ++ks)
            a[ks] = *reinterpret_cast<const i4_t*>(&h8[rp][l15][64 * ks + 16 * lgp]);

        i4_t acc[4][2];
#pragma unroll
        for (int gt = 0; gt < 4; ++gt)
#pragma unroll
            for (int jt = 0; jt < 2; ++jt) acc[gt][jt] = (i4_t){0, 0, 0, 0};

#pragma unroll
        for (int gt = 0; gt < 4; ++gt)
#pragma unroll
            for (int ks = 0; ks < 4; ++ks)
                acc[gt][0] = __builtin_amdgcn_mfma_i32_16x16x64_i8(
                    a[ks], wreg[gt][ks], acc[gt][0], 0, 0, 0);
#pragma unroll
        for (int gt = 0; gt < 4; ++gt)
#pragma unroll
            for (int ks = 0; ks < 4; ++ks) {
                i4_t b = wsh[wbase + (gt * 4 + ks) * 64];
                acc[gt][1] = __builtin_amdgcn_mfma_i32_16x16x64_i8(
                    a[ks], b, acc[gt][1], 0, 0, 0);
            }

        // gates + state update (VALU phase)
#pragma unroll
        for (int jt = 0; jt < 2; ++jt) {
            int j = 32 * w + 16 * jt + l15;
#pragma unroll
            for (int r = 0; r < 4; ++r) {
                float pi = dq[0][jt] * (float)acc[0][jt][r] + bf2f(xv[0][jt][r]);
                float pf = dq[1][jt] * (float)acc[1][jt][r] + bf2f(xv[1][jt][r]);
                float pg = dq[2][jt] * (float)acc[2][jt][r] + bf2f(xv[2][jt][r]);
                float po = dq[3][jt] * (float)acc[3][jt][r] + bf2f(xv[3][jt][r]);
                float iv = sigf(pi), fv = sigf(pf), ov = sigf(po);
                float gv = tanh2_(pg);
                float cn = fv * c[jt][r] + iv * gv;
                c[jt][r] = cn;
                float hv = ov * tanh2_(cn);
                int m = 4 * lgp + r;
                hs[((size_t)(16 * bh + m) * 1024 + t) * 512 + d * 256 + j] = f2bf(hv);
                h8[wp][m][j] = (signed char)(int)__builtin_rintf(hv * 127.f);
            }
        }
        if (s == 0) {
#pragma unroll
            for (int gt = 0; gt < 4; ++gt)
#pragma unroll
                for (int jt = 0; jt < 2; ++jt) dq[gt][jt] = swl[gt][jt] * (1.f / 127.f);
        }
        // barrier: drain LDS only (hs stores + next xv loads stay in flight)
        asm volatile("s_waitcnt lgkmcnt(0)" ::: "memory");
        __builtin_amdgcn_sched_barrier(0);
        __builtin_amdgcn_s_barrier();
    }
}

// ---------------- logits = hs @ Wout^T + b_out (N padded to 16) ----------------
__global__ __launch_bounds__(256) void logits_kernel(const unsigned short* hs,
        const unsigned short* wout_bf, const float* b_out, float* logits) {
    int w = threadIdx.x >> 6, l = threadIdx.x & 63, l15 = l & 15, lgp = l >> 4;
    int mt = blockIdx.x * 4 + w;         // 0..2047
    const unsigned short* arow = hs + (size_t)(16 * mt + l15) * 512 + 8 * lgp;
    const unsigned short* brow = wout_bf + (size_t)l15 * 512 + 8 * lgp;
    f4_t acc; acc[0] = 0.f; acc[1] = 0.f; acc[2] = 0.f; acc[3] = 0.f;
#pragma unroll
    for (int ks = 0; ks < 16; ++ks) {
        bf8_t a = *reinterpret_cast<const bf8_t*>(arow + 32 * ks);
        bf8_t b = *reinterpret_cast<const bf8_t*>(brow + 32 * ks);
        acc = mfma16(a, b, acc);
    }
    float bo = (l15 < NTAG) ? b_out[l15] : 0.0f;
#pragma unroll
    for (int r = 0; r < 4; ++r) {
        int bt = 16 * mt + 4 * lgp + r;
        logits[(size_t)bt * 16 + l15] = acc[r] + bo;
    }
}

// ---------------- Viterbi: one wave per sequence ----------------
__global__ __launch_bounds__(64) void viterbi_kernel(const float* logits, const float* crf,
                                                     float* out) {
    int b = blockIdx.x, j = threadIdx.x;
    __shared__ unsigned char bp[1024][16];
    __shared__ unsigned char pth[1024];
    float crfj[NTAG];
#pragma unroll
    for (int i = 0; i < NTAG; ++i)
        crfj[i] = (j < NTAG) ? crf[i * NTAG + j] : 0.0f;
    const float* lgt = logits + (size_t)b * 1024 * 16;
    float v = (j < NTAG) ? lgt[j] : -3.0e38f;
    float lt_nxt = (j < NTAG) ? lgt[16 + j] : 0.0f;
    for (int t = 1; t < 1024; ++t) {
        float lt = lt_nxt;
        if (t < 1023) lt_nxt = (j < NTAG) ? lgt[(t + 1) * 16 + j] : 0.0f;
        float best = -3.0e38f; int arg = 0;
#pragma unroll
        for (int i = 0; i < NTAG; ++i) {
            float s = __shfl(v, i) + crfj[i];
            if (s > best) { best = s; arg = i; }   // strict > keeps lowest index (jnp.argmax)
        }
        v = (j < NTAG) ? (lt + best) : -3.0e38f;
        if (j < 16) bp[t][j] = (unsigned char)arg;
    }
    float best = -3.0e38f; int tag = 0;
#pragma unroll
    for (int jj = 0; jj < NTAG; ++jj) {
        float s = __shfl(v, jj);
        if (s > best) { best = s; tag = jj; }
    }
    __syncthreads();
    if (j == 0) {
        out[b] = best;
        int tg = tag;
        pth[1023] = (unsigned char)tg;
        for (int t = 1023; t >= 1; --t) {
            tg = bp[t][tg];
            pth[t - 1] = (unsigned char)tg;
        }
    }
    __syncthreads();
    float* pout = out + 32 + (size_t)b * 1024;
    for (int t = j; t < 1024; t += 64)
        pout[t] = (float)pth[t];
}

extern "C" void kernel_launch(void* const* d_in, const int* in_sizes, int n_in,
                              void* d_out, int out_size, void* d_ws, size_t ws_size,
                              hipStream_t stream) {
    const int* sent = (const int*)d_in[0];
    const float* emb = (const float*)d_in[1];
    const float* wih_f = (const float*)d_in[2];
    const float* whh_f = (const float*)d_in[3];
    const float* bih_f = (const float*)d_in[4];
    const float* bhh_f = (const float*)d_in[5];
    const float* wih_b = (const float*)d_in[6];
    const float* whh_b = (const float*)d_in[7];
    const float* bih_b = (const float*)d_in[8];
    const float* bhh_b = (const float*)d_in[9];
    const float* h0 = (const float*)d_in[10];
    const float* c0 = (const float*)d_in[11];
    const float* wout = (const float*)d_in[12];
    const float* b_out = (const float*)d_in[13];
    const float* crf = (const float*)d_in[14];

    char* ws = (char*)d_ws;
    signed char* qw       = (signed char*)(ws + 0);               // 512 KiB
    float* sw             = (float*)(ws + 524288);                // 8 KiB
    unsigned short* wih_bf = (unsigned short*)(ws + 1048576);     // 1 MiB
    float* biasc          = (float*)(ws + 2097152);               // 8 KiB
    unsigned short* wout_bf = (unsigned short*)(ws + 2105344);    // 16 KiB
    unsigned short* xbf   = (unsigned short*)(ws + 2121728);      // 16 MiB
    unsigned short* xg2   = (unsigned short*)(ws + 18898944);     // 128 MiB
    unsigned short* hs    = (unsigned short*)(ws + 153116672);    // 32 MiB
    float* logits         = (float*)(ws + 186671104);             // 2 MiB
    float* out = (float*)d_out;

    hipLaunchKernelGGL(prep_kernel, dim3(2088), dim3(256), 0, stream,
                       wih_f, wih_b, bih_f, bhh_f, bih_b, bhh_b, wout,
                       wih_bf, biasc, wout_bf);
    hipLaunchKernelGGL(wquant_kernel, dim3(512), dim3(256), 0, stream,
                       whh_f, whh_b, qw, sw);
    hipLaunchKernelGGL(embed_kernel, dim3(8192), dim3(256), 0, stream, sent, emb, xbf);
    hipLaunchKernelGGL(xproj_kernel, dim3(1024, 16), dim3(256), 0, stream,
                       xbf, wih_bf, biasc, xg2);
    hipLaunchKernelGGL(lstm_kernel, dim3(4), dim3(512), 0, stream,
                       xg2, qw, sw, h0, c0, hs);
    hipLaunchKernelGGL(logits_kernel, dim3(512), dim3(256), 0, stream,
                       hs, wout_bf, b_out, logits);
    hipLaunchKernelGGL(viterbi_kernel, dim3(32), dim3(64), 0, stream, logits, crf, out);
}

// Round 6
// 2882.392 us; speedup vs baseline: 1.5884x; 1.5423x over previous
//
#include <hip/hip_runtime.h>
#include <hip/hip_bf16.h>
#include <cstdint>

#define B_ 32
#define T_ 1024
#define E_ 256
#define H_ 256
#define G_ 1024
#define NTAG 14

typedef __bf16 bf8_t __attribute__((ext_vector_type(8)));
typedef float f4_t __attribute__((ext_vector_type(4)));
typedef int i4_t __attribute__((ext_vector_type(4)));
typedef unsigned short u16x2 __attribute__((ext_vector_type(2)));
typedef unsigned short u16x4 __attribute__((ext_vector_type(4)));
typedef unsigned short u16x8 __attribute__((ext_vector_type(8)));

__device__ __forceinline__ unsigned short f2bf(float f) {
    unsigned u = __builtin_bit_cast(unsigned, f);
    u = u + 0x7FFFu + ((u >> 16) & 1u);
    return (unsigned short)(u >> 16);
}
__device__ __forceinline__ float bf2f(unsigned short s) {
    unsigned u = ((unsigned)s) << 16;
    return __builtin_bit_cast(float, u);
}
__device__ __forceinline__ float sigf(float x) { return 1.0f / (1.0f + __expf(-x)); }
// branch-free tanh: overflow-safe (exp->inf => 1; exp->0 => -1)
__device__ __forceinline__ float tanh2_(float x) {
    float e = __expf(2.0f * x);
    return 1.0f - 2.0f / (e + 1.0f);
}
__device__ __forceinline__ f4_t mfma16(bf8_t a, bf8_t b, f4_t c) {
    return __builtin_amdgcn_mfma_f32_16x16x32_bf16(a, b, c, 0, 0, 0);
}

// ---------------- prep: wih->bf16, combine biases, wout pad ----------------
__global__ __launch_bounds__(256) void prep_kernel(
        const float* wih_f, const float* wih_b,
        const float* bih_f, const float* bhh_f,
        const float* bih_b, const float* bhh_b,
        const float* wout,
        unsigned short* wih_bf, float* biasc, unsigned short* wout_bf) {
    int tid = blockIdx.x * 256 + threadIdx.x;
    if (tid < 524288) {                       // 2 x 262144: [d][1024][256]
        int d = tid >> 18, off = tid & 262143;
        wih_bf[tid] = f2bf((d ? wih_b : wih_f)[off]);
        return;
    }
    int t2 = tid - 524288;
    if (t2 < 8192) {                          // wout padded [16][512]
        int n = t2 >> 9, k = t2 & 511;
        wout_bf[t2] = (n < NTAG) ? f2bf(wout[n * 512 + k]) : (unsigned short)0;
        return;
    }
    int t3 = t2 - 8192;
    if (t3 < 2048) {                          // biasc [2][1024]
        int d = t3 >> 10, g = t3 & 1023;
        biasc[t3] = d ? (bih_b[g] + bhh_b[g]) : (bih_f[g] + bhh_f[g]);
    }
}

// ---------------- whh -> int8 with per-row scale ----------------
__global__ __launch_bounds__(256) void wquant_kernel(const float* whh_f, const float* whh_b,
                                                     signed char* qw, float* sw) {
    int row = blockIdx.x * 4 + (threadIdx.x >> 6);   // 0..2047 = [d][1024]
    int l = threadIdx.x & 63;
    int d = row >> 10, rr = row & 1023;
    const float* src = (d ? whh_b : whh_f) + (size_t)rr * 256;
    float4 v = *reinterpret_cast<const float4*>(src + 4 * l);
    float am = fmaxf(fmaxf(fabsf(v.x), fabsf(v.y)), fmaxf(fabsf(v.z), fabsf(v.w)));
#pragma unroll
    for (int off = 1; off < 64; off <<= 1)
        am = fmaxf(am, __shfl_xor(am, off));
    am = fmaxf(am, 1e-20f);
    float inv = 127.f / am;
    int q0 = (int)__builtin_rintf(v.x * inv), q1 = (int)__builtin_rintf(v.y * inv);
    int q2 = (int)__builtin_rintf(v.z * inv), q3 = (int)__builtin_rintf(v.w * inv);
    unsigned u = (q0 & 255) | ((q1 & 255) << 8) | ((q2 & 255) << 16) | ((q3 & 255) << 24);
    *reinterpret_cast<unsigned*>(qw + (size_t)row * 256 + 4 * l) = u;
    if (l == 0) sw[row] = am / 127.f;
}

// ---------------- embedding gather -> bf16 ----------------
__global__ __launch_bounds__(256) void embed_kernel(const int* sent, const float* emb,
                                                    unsigned short* xbf) {
    int tid = blockIdx.x * 256 + threadIdx.x; // 32768*64 threads
    int bt = tid >> 6;
    int e0 = (tid & 63) << 2;
    int tok = sent[bt];
    float4 v = *reinterpret_cast<const float4*>(emb + (size_t)tok * E_ + e0);
    u16x4 o;
    o[0] = f2bf(v.x); o[1] = f2bf(v.y); o[2] = f2bf(v.z); o[3] = f2bf(v.w);
    *reinterpret_cast<u16x4*>(xbf + (size_t)bt * E_ + e0) = o;
}

// ---- input projection -> xg3[d][b2 16][t][n 1024][2 m], coalesced via LDS transpose ----
// block = (t, d*8 + bh*4 + ns): M-tile = 16 batch rows (bh half) at fixed t.
__global__ __launch_bounds__(256) void xproj_kernel(const unsigned short* xbf,
        const unsigned short* wih_bf, const float* biasc, unsigned short* xg3) {
    int t = blockIdx.x;                  // 0..1023
    int y = blockIdx.y;                  // d*8 + bh*4 + ns
    int ns = y & 3, bh = (y >> 2) & 1, d = y >> 3;
    int w = threadIdx.x >> 6, l = threadIdx.x & 63;
    int l15 = l & 15, lgp = l >> 4;
    __shared__ unsigned short sh[256][16];

    bf8_t a[8];
    const unsigned short* arow = xbf + ((size_t)(16 * bh + l15) * 1024 + t) * E_ + 8 * lgp;
#pragma unroll
    for (int ks = 0; ks < 8; ++ks)
        a[ks] = *reinterpret_cast<const bf8_t*>(arow + 32 * ks);

    int nbase = ns * 256 + w * 64;
    const unsigned short* wd = wih_bf + (size_t)d * 262144;
    f4_t acc[4];
#pragma unroll
    for (int p = 0; p < 4; ++p) { acc[p][0] = 0.f; acc[p][1] = 0.f; acc[p][2] = 0.f; acc[p][3] = 0.f; }
#pragma unroll
    for (int p = 0; p < 4; ++p) {
        int n = nbase + 16 * p + l15;
        const unsigned short* brow = wd + (size_t)n * E_ + 8 * lgp;
#pragma unroll
        for (int ks = 0; ks < 8; ++ks) {
            bf8_t b = *reinterpret_cast<const bf8_t*>(brow + 32 * ks);
            acc[p] = mfma16(a[ks], b, acc[p]);
        }
    }
#pragma unroll
    for (int p = 0; p < 4; ++p) {
        int n = nbase + 16 * p + l15;
        float bias = biasc[d * G_ + n];
#pragma unroll
        for (int r = 0; r < 4; ++r)
            sh[w * 64 + 16 * p + l15][4 * lgp + r] = f2bf(acc[p][r] + bias);
    }
    __syncthreads();
    // writeout: thread q owns n = ns*256+q; 8 stores of one m-pair (4B) each
    int q = threadIdx.x;
    int n = ns * 256 + q;
#pragma unroll
    for (int p2 = 0; p2 < 8; ++p2) {
        int b2 = bh * 8 + p2;
        u16x2 v; v[0] = sh[q][2 * p2]; v[1] = sh[q][2 * p2 + 1];
        *reinterpret_cast<u16x2*>(xg3 +
            (((size_t)(d * 16 + b2) * 1024 + t) * 1024 + n) * 2) = v;
    }
}

// ------- recurrence: 32 independent WGs = (dir, batch-pair), i8 weights 3/4 reg + 1/4 LDS ----
__global__ __launch_bounds__(512, 2) void lstm_kernel(const unsigned short* xg3,
        const signed char* qw, const float* sw, const float* h0, const float* c0,
        unsigned short* hs) {
    int bid = blockIdx.x;            // 0..31
    int b2 = bid & 15, d = bid >> 4;
    int tid = threadIdx.x;
    int w = tid >> 6, l = tid & 63, l15 = l & 15, lgp = l >> 4;

    __shared__ __attribute__((aligned(16))) signed char h8[2][2][288];
    __shared__ i4_t wsh[4096];       // 64 KiB: ks=3 weight quarter
    __shared__ float red_sh[8];

    const signed char* qwd = qw + (size_t)d * 262144;
    float swl[4][2];

    // ks 0..2 weights -> registers (24 quads = 96 VGPR)
    i4_t wreg[4][2][3];
#pragma unroll
    for (int gt = 0; gt < 4; ++gt)
#pragma unroll
        for (int jt = 0; jt < 2; ++jt) {
            int n = 256 * gt + 32 * w + 16 * jt + l15;
            swl[gt][jt] = sw[d * 1024 + n];
#pragma unroll
            for (int ks = 0; ks < 3; ++ks)
                wreg[gt][jt][ks] = *reinterpret_cast<const i4_t*>(
                    qwd + (size_t)n * 256 + 64 * ks + 16 * lgp);
        }
#pragma unroll
    for (int gt = 0; gt < 4; ++gt)
#pragma unroll
        for (int jt = 0; jt < 2; ++jt)
#pragma unroll
            for (int ks = 0; ks < 3; ++ks)
                asm volatile("" : "+v"(wreg[gt][jt][ks]));   // keep resident

    // ks=3 weights -> LDS
#pragma unroll
    for (int gt = 0; gt < 4; ++gt)
#pragma unroll
        for (int jt = 0; jt < 2; ++jt) {
            int n = 256 * gt + 32 * w + 16 * jt + l15;
            wsh[(w * 8 + gt * 2 + jt) * 64 + l] = *reinterpret_cast<const i4_t*>(
                qwd + (size_t)n * 256 + 192 + 16 * lgp);
        }

    // c init (valid on lanes lgp==0; loads harmless elsewhere)
    float c[2][2];
#pragma unroll
    for (int jt = 0; jt < 2; ++jt)
#pragma unroll
        for (int r = 0; r < 2; ++r)
            c[jt][r] = c0[((size_t)d * 32 + b2 * 2 + r) * 256 + 32 * w + 16 * jt + l15];

    // h0: block amax -> step-0 scale, quantize rows {0,1} into parity-1
    float v0 = h0[((size_t)d * 32 + b2 * 2 + (tid >> 8)) * 256 + (tid & 255)];
    float am = fabsf(v0);
#pragma unroll
    for (int off = 1; off < 64; off <<= 1)
        am = fmaxf(am, __shfl_xor(am, off));
    if (l == 0) red_sh[w] = am;
    __syncthreads();
    float bmax = red_sh[0];
#pragma unroll
    for (int q = 1; q < 8; ++q) bmax = fmaxf(bmax, red_sh[q]);
    bmax = fmaxf(bmax, 1e-20f);
    float s0 = bmax / 127.f;
    h8[1][tid >> 8][tid & 255] = (signed char)(int)__builtin_rintf(v0 * (127.f / bmax));
    __syncthreads();   // weights staged + h(-1) ready

    const unsigned short* xbase = xg3 + (size_t)(d * 16 + b2) * 1024 * 2048;
    float dq[4][2];
#pragma unroll
    for (int gt = 0; gt < 4; ++gt)
#pragma unroll
        for (int jt = 0; jt < 2; ++jt) dq[gt][jt] = swl[gt][jt] * s0;

    bool act = (lgp == 0);

    for (int s = 0; s < 1024; ++s) {
        int t = d ? (1023 - s) : s;
        int rp = (s + 1) & 1, wp = s & 1;

        // gate pre-activations (m-pair per lane; only lanes lgp==0 need them)
        u16x2 xv[4][2];
        const unsigned short* xt = xbase + (size_t)t * 2048;
        if (act) {
#pragma unroll
            for (int gt = 0; gt < 4; ++gt)
#pragma unroll
                for (int jt = 0; jt < 2; ++jt) {
                    int n = 256 * gt + 32 * w + 16 * jt + l15;
                    xv[gt][jt] = *reinterpret_cast<const u16x2*>(xt + n * 2);
                }
        }

        i4_t a[4];
#pragma unroll
        for (int ks = 0; ks < 4; ++ks)
            a[ks] = *reinterpret_cast<const i4_t*>(&h8[rp][l15 & 1][64 * ks + 16 * lgp]);

        i4_t acc[4][2];
#pragma unroll
        for (int gt = 0; gt < 4; ++gt)
#pragma unroll
            for (int jt = 0; jt < 2; ++jt) acc[gt][jt] = (i4_t){0, 0, 0, 0};

#pragma unroll
        for (int gt = 0; gt < 4; ++gt)
#pragma unroll
            for (int jt = 0; jt < 2; ++jt) {
#pragma unroll
                for (int ks = 0; ks < 3; ++ks)
                    acc[gt][jt] = __builtin_amdgcn_mfma_i32_16x16x64_i8(
                        a[ks], wreg[gt][jt][ks], acc[gt][jt], 0, 0, 0);
                i4_t b = wsh[(w * 8 + gt * 2 + jt) * 64 + l];
                acc[gt][jt] = __builtin_amdgcn_mfma_i32_16x16x64_i8(
                    a[3], b, acc[gt][jt], 0, 0, 0);
            }

        // gates + state update: only D rows m=0,1 are real (lanes lgp==0, r<2)
        if (act) {
#pragma unroll
            for (int jt = 0; jt < 2; ++jt) {
                int j = 32 * w + 16 * jt + l15;
#pragma unroll
                for (int r = 0; r < 2; ++r) {
                    float pi = dq[0][jt] * (float)acc[0][jt][r] + bf2f(xv[0][jt][r]);
                    float pf = dq[1][jt] * (float)acc[1][jt][r] + bf2f(xv[1][jt][r]);
                    float pg = dq[2][jt] * (float)acc[2][jt][r] + bf2f(xv[2][jt][r]);
                    float po = dq[3][jt] * (float)acc[3][jt][r] + bf2f(xv[3][jt][r]);
                    float iv = sigf(pi), fv = sigf(pf), ov = sigf(po);
                    float gv = tanh2_(pg);
                    float cn = fv * c[jt][r] + iv * gv;
                    c[jt][r] = cn;
                    float hv = ov * tanh2_(cn);
                    hs[((size_t)(b2 * 2 + r) * 1024 + t) * 512 + d * 256 + j] = f2bf(hv);
                    h8[wp][r][j] = (signed char)(int)__builtin_rintf(hv * 127.f);
                }
            }
        }
        if (s == 0) {
#pragma unroll
            for (int gt = 0; gt < 4; ++gt)
#pragma unroll
                for (int jt = 0; jt < 2; ++jt) dq[gt][jt] = swl[gt][jt] * (1.f / 127.f);
        }
        // barrier: drain LDS only (hs stores + next xv loads stay in flight)
        asm volatile("s_waitcnt lgkmcnt(0)" ::: "memory");
        __builtin_amdgcn_sched_barrier(0);
        __builtin_amdgcn_s_barrier();
    }
}

// ---------------- logits = hs @ Wout^T + b_out (N padded to 16) ----------------
__global__ __launch_bounds__(256) void logits_kernel(const unsigned short* hs,
        const unsigned short* wout_bf, const float* b_out, float* logits) {
    int w = threadIdx.x >> 6, l = threadIdx.x & 63, l15 = l & 15, lgp = l >> 4;
    int mt = blockIdx.x * 4 + w;         // 0..2047
    const unsigned short* arow = hs + (size_t)(16 * mt + l15) * 512 + 8 * lgp;
    const unsigned short* brow = wout_bf + (size_t)l15 * 512 + 8 * lgp;
    f4_t acc; acc[0] = 0.f; acc[1] = 0.f; acc[2] = 0.f; acc[3] = 0.f;
#pragma unroll
    for (int ks = 0; ks < 16; ++ks) {
        bf8_t a = *reinterpret_cast<const bf8_t*>(arow + 32 * ks);
        bf8_t b = *reinterpret_cast<const bf8_t*>(brow + 32 * ks);
        acc = mfma16(a, b, acc);
    }
    float bo = (l15 < NTAG) ? b_out[l15] : 0.0f;
#pragma unroll
    for (int r = 0; r < 4; ++r) {
        int bt = 16 * mt + 4 * lgp + r;
        logits[(size_t)bt * 16 + l15] = acc[r] + bo;
    }
}

// ---------------- Viterbi: one wave per sequence ----------------
__global__ __launch_bounds__(64) void viterbi_kernel(const float* logits, const float* crf,
                                                     float* out) {
    int b = blockIdx.x, j = threadIdx.x;
    __shared__ unsigned char bp[1024][16];
    __shared__ unsigned char pth[1024];
    float crfj[NTAG];
#pragma unroll
    for (int i = 0; i < NTAG; ++i)
        crfj[i] = (j < NTAG) ? crf[i * NTAG + j] : 0.0f;
    const float* lgt = logits + (size_t)b * 1024 * 16;
    float v = (j < NTAG) ? lgt[j] : -3.0e38f;
    float lt_nxt = (j < NTAG) ? lgt[16 + j] : 0.0f;
    for (int t = 1; t < 1024; ++t) {
        float lt = lt_nxt;
        if (t < 1023) lt_nxt = (j < NTAG) ? lgt[(t + 1) * 16 + j] : 0.0f;
        float best = -3.0e38f; int arg = 0;
#pragma unroll
        for (int i = 0; i < NTAG; ++i) {
            float s = __shfl(v, i) + crfj[i];
            if (s > best) { best = s; arg = i; }   // strict > keeps lowest index (jnp.argmax)
        }
        v = (j < NTAG) ? (lt + best) : -3.0e38f;
        if (j < 16) bp[t][j] = (unsigned char)arg;
    }
    float best = -3.0e38f; int tag = 0;
#pragma unroll
    for (int jj = 0; jj < NTAG; ++jj) {
        float s = __shfl(v, jj);
        if (s > best) { best = s; tag = jj; }
    }
    __syncthreads();
    if (j == 0) {
        out[b] = best;
        int tg = tag;
        pth[1023] = (unsigned char)tg;
        for (int t = 1023; t >= 1; --t) {
            tg = bp[t][tg];
            pth[t - 1] = (unsigned char)tg;
        }
    }
    __syncthreads();
    float* pout = out + 32 + (size_t)b * 1024;
    for (int t = j; t < 1024; t += 64)
        pout[t] = (float)pth[t];
}

extern "C" void kernel_launch(void* const* d_in, const int* in_sizes, int n_in,
                              void* d_out, int out_size, void* d_ws, size_t ws_size,
                              hipStream_t stream) {
    const int* sent = (const int*)d_in[0];
    const float* emb = (const float*)d_in[1];
    const float* wih_f = (const float*)d_in[2];
    const float* whh_f = (const float*)d_in[3];
    const float* bih_f = (const float*)d_in[4];
    const float* bhh_f = (const float*)d_in[5];
    const float* wih_b = (const float*)d_in[6];
    const float* whh_b = (const float*)d_in[7];
    const float* bih_b = (const float*)d_in[8];
    const float* bhh_b = (const float*)d_in[9];
    const float* h0 = (const float*)d_in[10];
    const float* c0 = (const float*)d_in[11];
    const float* wout = (const float*)d_in[12];
    const float* b_out = (const float*)d_in[13];
    const float* crf = (const float*)d_in[14];

    char* ws = (char*)d_ws;
    signed char* qw       = (signed char*)(ws + 0);               // 512 KiB
    float* sw             = (float*)(ws + 524288);                // 8 KiB
    unsigned short* wih_bf = (unsigned short*)(ws + 1048576);     // 1 MiB
    float* biasc          = (float*)(ws + 2097152);               // 8 KiB
    unsigned short* wout_bf = (unsigned short*)(ws + 2105344);    // 16 KiB
    unsigned short* xbf   = (unsigned short*)(ws + 2121728);      // 16 MiB
    unsigned short* xg3   = (unsigned short*)(ws + 18898944);     // 128 MiB
    unsigned short* hs    = (unsigned short*)(ws + 153116672);    // 32 MiB
    float* logits         = (float*)(ws + 186671104);             // 2 MiB
    float* out = (float*)d_out;

    hipLaunchKernelGGL(prep_kernel, dim3(2088), dim3(256), 0, stream,
                       wih_f, wih_b, bih_f, bhh_f, bih_b, bhh_b, wout,
                       wih_bf, biasc, wout_bf);
    hipLaunchKernelGGL(wquant_kernel, dim3(512), dim3(256), 0, stream,
                       whh_f, whh_b, qw, sw);
    hipLaunchKernelGGL(embed_kernel, dim3(8192), dim3(256), 0, stream, sent, emb, xbf);
    hipLaunchKernelGGL(xproj_kernel, dim3(1024, 16), dim3(256), 0, stream,
                       xbf, wih_bf, biasc, xg3);
    hipLaunchKernelGGL(lstm_kernel, dim3(32), dim3(512), 0, stream,
                       xg3, qw, sw, h0, c0, hs);
    hipLaunchKernelGGL(logits_kernel, dim3(512), dim3(256), 0, stream,
                       hs, wout_bf, b_out, logits);
    hipLaunchKernelGGL(viterbi_kernel, dim3(32), dim3(64), 0, stream, logits, crf, out);
}

// Round 7
// 2100.163 us; speedup vs baseline: 2.1800x; 1.3725x over previous
//
#include <hip/hip_runtime.h>
#include <hip/hip_bf16.h>
#include <cstdint>

#define B_ 32
#define T_ 1024
#define E_ 256
#define H_ 256
#define G_ 1024
#define NTAG 14

typedef __bf16 bf8_t __attribute__((ext_vector_type(8)));
typedef float f4_t __attribute__((ext_vector_type(4)));
typedef int i4_t __attribute__((ext_vector_type(4)));
typedef unsigned short u16x4 __attribute__((ext_vector_type(4)));

__device__ __forceinline__ unsigned short f2bf(float f) {
    unsigned u = __builtin_bit_cast(unsigned, f);
    u = u + 0x7FFFu + ((u >> 16) & 1u);
    return (unsigned short)(u >> 16);
}
__device__ __forceinline__ float bf2f(unsigned short s) {
    unsigned u = ((unsigned)s) << 16;
    return __builtin_bit_cast(float, u);
}
__device__ __forceinline__ float sigf(float x) { return 1.0f / (1.0f + __expf(-x)); }
// branch-free tanh: overflow-safe (exp->inf => 1; exp->0 => -1)
__device__ __forceinline__ float tanh2_(float x) {
    float e = __expf(2.0f * x);
    return 1.0f - 2.0f / (e + 1.0f);
}
__device__ __forceinline__ f4_t mfma16(bf8_t a, bf8_t b, f4_t c) {
    return __builtin_amdgcn_mfma_f32_16x16x32_bf16(a, b, c, 0, 0, 0);
}

// ---------------- prep: wih->bf16, combine biases, wout pad ----------------
__global__ __launch_bounds__(256) void prep_kernel(
        const float* wih_f, const float* wih_b,
        const float* bih_f, const float* bhh_f,
        const float* bih_b, const float* bhh_b,
        const float* wout,
        unsigned short* wih_bf, float* biasc, unsigned short* wout_bf) {
    int tid = blockIdx.x * 256 + threadIdx.x;
    if (tid < 524288) {                       // 2 x 262144: [d][1024][256]
        int d = tid >> 18, off = tid & 262143;
        wih_bf[tid] = f2bf((d ? wih_b : wih_f)[off]);
        return;
    }
    int t2 = tid - 524288;
    if (t2 < 8192) {                          // wout padded [16][512]
        int n = t2 >> 9, k = t2 & 511;
        wout_bf[t2] = (n < NTAG) ? f2bf(wout[n * 512 + k]) : (unsigned short)0;
        return;
    }
    int t3 = t2 - 8192;
    if (t3 < 2048) {                          // biasc [2][1024]
        int d = t3 >> 10, g = t3 & 1023;
        biasc[t3] = d ? (bih_b[g] + bhh_b[g]) : (bih_f[g] + bhh_f[g]);
    }
}

// ---------------- whh -> int8 with per-row scale ----------------
__global__ __launch_bounds__(256) void wquant_kernel(const float* whh_f, const float* whh_b,
                                                     signed char* qw, float* sw) {
    int row = blockIdx.x * 4 + (threadIdx.x >> 6);   // 0..2047 = [d][1024]
    int l = threadIdx.x & 63;
    int d = row >> 10, rr = row & 1023;
    const float* src = (d ? whh_b : whh_f) + (size_t)rr * 256;
    float4 v = *reinterpret_cast<const float4*>(src + 4 * l);
    float am = fmaxf(fmaxf(fabsf(v.x), fabsf(v.y)), fmaxf(fabsf(v.z), fabsf(v.w)));
#pragma unroll
    for (int off = 1; off < 64; off <<= 1)
        am = fmaxf(am, __shfl_xor(am, off));
    am = fmaxf(am, 1e-20f);
    float inv = 127.f / am;
    int q0 = (int)__builtin_rintf(v.x * inv), q1 = (int)__builtin_rintf(v.y * inv);
    int q2 = (int)__builtin_rintf(v.z * inv), q3 = (int)__builtin_rintf(v.w * inv);
    unsigned u = (q0 & 255) | ((q1 & 255) << 8) | ((q2 & 255) << 16) | ((q3 & 255) << 24);
    *reinterpret_cast<unsigned*>(qw + (size_t)row * 256 + 4 * l) = u;
    if (l == 0) sw[row] = am / 127.f;
}

// ---------------- embedding gather -> bf16 ----------------
__global__ __launch_bounds__(256) void embed_kernel(const int* sent, const float* emb,
                                                    unsigned short* xbf) {
    int tid = blockIdx.x * 256 + threadIdx.x; // 32768*64 threads
    int bt = tid >> 6;
    int e0 = (tid & 63) << 2;
    int tok = sent[bt];
    float4 v = *reinterpret_cast<const float4*>(emb + (size_t)tok * E_ + e0);
    u16x4 o;
    o[0] = f2bf(v.x); o[1] = f2bf(v.y); o[2] = f2bf(v.z); o[3] = f2bf(v.w);
    *reinterpret_cast<u16x4*>(xbf + (size_t)bt * E_ + e0) = o;
}

// ---- input projection -> xg4[d*16+b2][t][m 2][1024 n], coalesced via LDS transpose ----
__global__ __launch_bounds__(256) void xproj_kernel(const unsigned short* xbf,
        const unsigned short* wih_bf, const float* biasc, unsigned short* xg4) {
    int t = blockIdx.x;                  // 0..1023
    int y = blockIdx.y;                  // d*8 + bh*4 + ns
    int ns = y & 3, bh = (y >> 2) & 1, d = y >> 3;
    int w = threadIdx.x >> 6, l = threadIdx.x & 63;
    int l15 = l & 15, lgp = l >> 4;
    __shared__ unsigned short sh[256][16];

    bf8_t a[8];
    const unsigned short* arow = xbf + ((size_t)(16 * bh + l15) * 1024 + t) * E_ + 8 * lgp;
#pragma unroll
    for (int ks = 0; ks < 8; ++ks)
        a[ks] = *reinterpret_cast<const bf8_t*>(arow + 32 * ks);

    int nbase = ns * 256 + w * 64;
    const unsigned short* wd = wih_bf + (size_t)d * 262144;
    f4_t acc[4];
#pragma unroll
    for (int p = 0; p < 4; ++p) { acc[p][0] = 0.f; acc[p][1] = 0.f; acc[p][2] = 0.f; acc[p][3] = 0.f; }
#pragma unroll
    for (int p = 0; p < 4; ++p) {
        int n = nbase + 16 * p + l15;
        const unsigned short* brow = wd + (size_t)n * E_ + 8 * lgp;
#pragma unroll
        for (int ks = 0; ks < 8; ++ks) {
            bf8_t b = *reinterpret_cast<const bf8_t*>(brow + 32 * ks);
            acc[p] = mfma16(a[ks], b, acc[p]);
        }
    }
#pragma unroll
    for (int p = 0; p < 4; ++p) {
        int n = nbase + 16 * p + l15;
        float bias = biasc[d * G_ + n];
#pragma unroll
        for (int r = 0; r < 4; ++r)
            sh[w * 64 + 16 * p + l15][4 * lgp + r] = f2bf(acc[p][r] + bias);
    }
    __syncthreads();
    // writeout: thread q owns n = ns*256+q; 16 coalesced scalar stores
    int q = threadIdx.x;
#pragma unroll
    for (int p = 0; p < 8; ++p) {
        int b2g = 8 * bh + p;
        size_t base = ((size_t)(d * 16 + b2g) * 1024 + t) * 2048 + ns * 256 + q;
        xg4[base]        = sh[q][2 * p];      // m=0
        xg4[base + 1024] = sh[q][2 * p + 1];  // m=1
    }
}

// ------- recurrence: 32 WGs = (dir, batch-pair); MFMA -> LDS gacc -> 1 cell/lane ----
__global__ __launch_bounds__(512, 2) void lstm_kernel(const unsigned short* xg4,
        const signed char* qw, const float* sw, const float* h0, const float* c0,
        unsigned short* hs) {
    int bid = blockIdx.x;            // 0..31
    int b2 = bid & 15, d = bid >> 4;
    int tid = threadIdx.x;
    int w = tid >> 6, l = tid & 63, l15 = l & 15, lgp = l >> 4;

    __shared__ __attribute__((aligned(16))) signed char h8[2][320];  // single buffer
    __shared__ i4_t wsh[4096];       // 64 KiB: ks=3 weight quarter
    __shared__ int gacc[2][1024];    // 8 KiB gate pre-activations
    __shared__ float red_sh[8];

    const signed char* qwd = qw + (size_t)d * 262144;

    // ks 0..2 weights -> registers (24 quads = 96 VGPR)
    i4_t wreg[4][2][3];
#pragma unroll
    for (int gt = 0; gt < 4; ++gt)
#pragma unroll
        for (int jt = 0; jt < 2; ++jt) {
            int n = 256 * gt + 32 * w + 16 * jt + l15;
#pragma unroll
            for (int ks = 0; ks < 3; ++ks)
                wreg[gt][jt][ks] = *reinterpret_cast<const i4_t*>(
                    qwd + (size_t)n * 256 + 64 * ks + 16 * lgp);
        }
#pragma unroll
    for (int gt = 0; gt < 4; ++gt)
#pragma unroll
        for (int jt = 0; jt < 2; ++jt)
#pragma unroll
            for (int ks = 0; ks < 3; ++ks)
                asm volatile("" : "+v"(wreg[gt][jt][ks]));   // keep resident

    // ks=3 weights -> LDS
#pragma unroll
    for (int gt = 0; gt < 4; ++gt)
#pragma unroll
        for (int jt = 0; jt < 2; ++jt) {
            int n = 256 * gt + 32 * w + 16 * jt + l15;
            wsh[(w * 8 + gt * 2 + jt) * 64 + l] = *reinterpret_cast<const i4_t*>(
                qwd + (size_t)n * 256 + 192 + 16 * lgp);
        }

    // ---- cell coords (epilogue): one cell per thread ----
    int cm = tid >> 8, cj = tid & 255;
    float swv[4];
#pragma unroll
    for (int gt = 0; gt < 4; ++gt)
        swv[gt] = sw[d * 1024 + 256 * gt + cj];
    float c = c0[((size_t)d * 32 + b2 * 2 + cm) * 256 + cj];

    // h0: block amax -> step-0 scale, quantize rows {0,1}
    float v0 = h0[((size_t)d * 32 + b2 * 2 + cm) * 256 + cj];
    float am = fabsf(v0);
#pragma unroll
    for (int off = 1; off < 64; off <<= 1)
        am = fmaxf(am, __shfl_xor(am, off));
    if (l == 0) red_sh[w] = am;
    __syncthreads();
    float bmax = red_sh[0];
#pragma unroll
    for (int q = 1; q < 8; ++q) bmax = fmaxf(bmax, red_sh[q]);
    bmax = fmaxf(bmax, 1e-20f);
    float s0 = bmax / 127.f;
    h8[cm][cj] = (signed char)(int)__builtin_rintf(v0 * (127.f / bmax));

    float dq[4];
#pragma unroll
    for (int gt = 0; gt < 4; ++gt) dq[gt] = swv[gt] * s0;

    // ---- streaming pointers (t is monotone) ----
    int t0 = d ? 1023 : 0;
    int xinc = d ? -2048 : 2048;
    int hinc = d ? -512 : 512;
    const unsigned short* xq = xg4 + ((size_t)(d * 16 + b2) * 1024 + t0) * 2048
                               + cm * 1024 + cj;
    unsigned short* hsp = hs + ((size_t)(b2 * 2 + cm) * 1024 + t0) * 512 + d * 256 + cj;

    unsigned short xc[4], xn[4];
#pragma unroll
    for (int gt = 0; gt < 4; ++gt) xc[gt] = xq[256 * gt];

    __syncthreads();   // weights staged + h(-1) ready

    for (int s = 0; s < 1024; ++s) {
        // prefetch next step's xg values (full step of latency cover)
        if (s < 1023) {
            xq += xinc;
#pragma unroll
            for (int gt = 0; gt < 4; ++gt) xn[gt] = xq[256 * gt];
        }

        // A fragments (rows 0,1 broadcast-duplicated)
        i4_t a[4];
#pragma unroll
        for (int ks = 0; ks < 4; ++ks)
            a[ks] = *reinterpret_cast<const i4_t*>(&h8[l15 & 1][64 * ks + 16 * lgp]);

        i4_t acc[4][2];
#pragma unroll
        for (int gt = 0; gt < 4; ++gt)
#pragma unroll
            for (int jt = 0; jt < 2; ++jt) acc[gt][jt] = (i4_t){0, 0, 0, 0};

#pragma unroll
        for (int gt = 0; gt < 4; ++gt)
#pragma unroll
            for (int jt = 0; jt < 2; ++jt) {
#pragma unroll
                for (int ks = 0; ks < 3; ++ks)
                    acc[gt][jt] = __builtin_amdgcn_mfma_i32_16x16x64_i8(
                        a[ks], wreg[gt][jt][ks], acc[gt][jt], 0, 0, 0);
                i4_t b = wsh[(w * 8 + gt * 2 + jt) * 64 + l];
                acc[gt][jt] = __builtin_amdgcn_mfma_i32_16x16x64_i8(
                    a[3], b, acc[gt][jt], 0, 0, 0);
            }

        // stage pre-activations into LDS (act lanes only; conflict-free)
        if (lgp == 0) {
#pragma unroll
            for (int gt = 0; gt < 4; ++gt)
#pragma unroll
                for (int jt = 0; jt < 2; ++jt) {
                    int n = 256 * gt + 32 * w + 16 * jt + l15;
                    gacc[0][n] = acc[gt][jt][0];
                    gacc[1][n] = acc[gt][jt][1];
                }
        }
        asm volatile("s_waitcnt lgkmcnt(0)" ::: "memory");
        __builtin_amdgcn_sched_barrier(0);
        __builtin_amdgcn_s_barrier();

        // epilogue: every lane computes its one cell (cm, cj)
        int gi = gacc[cm][cj];
        int gf = gacc[cm][cj + 256];
        int gg = gacc[cm][cj + 512];
        int go = gacc[cm][cj + 768];
        float pi = dq[0] * (float)gi + bf2f(xc[0]);
        float pf = dq[1] * (float)gf + bf2f(xc[1]);
        float pg = dq[2] * (float)gg + bf2f(xc[2]);
        float po = dq[3] * (float)go + bf2f(xc[3]);
        float iv = sigf(pi), fv = sigf(pf), ov = sigf(po);
        float gv = tanh2_(pg);
        float cn = fv * c + iv * gv;
        c = cn;
        float hv = ov * tanh2_(cn);
        *hsp = f2bf(hv);
        hsp += hinc;
        h8[cm][cj] = (signed char)(int)__builtin_rintf(hv * 127.f);

        if (s == 0) {
#pragma unroll
            for (int gt = 0; gt < 4; ++gt) dq[gt] = swv[gt] * (1.f / 127.f);
        }
#pragma unroll
        for (int gt = 0; gt < 4; ++gt) xc[gt] = xn[gt];

        asm volatile("s_waitcnt lgkmcnt(0)" ::: "memory");
        __builtin_amdgcn_sched_barrier(0);
        __builtin_amdgcn_s_barrier();
    }
}

// ---------------- logits = hs @ Wout^T + b_out (N padded to 16) ----------------
__global__ __launch_bounds__(256) void logits_kernel(const unsigned short* hs,
        const unsigned short* wout_bf, const float* b_out, float* logits) {
    int w = threadIdx.x >> 6, l = threadIdx.x & 63, l15 = l & 15, lgp = l >> 4;
    int mt = blockIdx.x * 4 + w;         // 0..2047
    const unsigned short* arow = hs + (size_t)(16 * mt + l15) * 512 + 8 * lgp;
    const unsigned short* brow = wout_bf + (size_t)l15 * 512 + 8 * lgp;
    f4_t acc; acc[0] = 0.f; acc[1] = 0.f; acc[2] = 0.f; acc[3] = 0.f;
#pragma unroll
    for (int ks = 0; ks < 16; ++ks) {
        bf8_t a = *reinterpret_cast<const bf8_t*>(arow + 32 * ks);
        bf8_t b = *reinterpret_cast<const bf8_t*>(brow + 32 * ks);
        acc = mfma16(a, b, acc);
    }
    float bo = (l15 < NTAG) ? b_out[l15] : 0.0f;
#pragma unroll
    for (int r = 0; r < 4; ++r) {
        int bt = 16 * mt + 4 * lgp + r;
        logits[(size_t)bt * 16 + l15] = acc[r] + bo;
    }
}

// ---------------- Viterbi: one wave per sequence ----------------
__global__ __launch_bounds__(64) void viterbi_kernel(const float* logits, const float* crf,
                                                     float* out) {
    int b = blockIdx.x, j = threadIdx.x;
    __shared__ unsigned char bp[1024][16];
    __shared__ unsigned char pth[1024];
    float crfj[NTAG];
#pragma unroll
    for (int i = 0; i < NTAG; ++i)
        crfj[i] = (j < NTAG) ? crf[i * NTAG + j] : 0.0f;
    const float* lgt = logits + (size_t)b * 1024 * 16;
    float v = (j < NTAG) ? lgt[j] : -3.0e38f;
    float lt_nxt = (j < NTAG) ? lgt[16 + j] : 0.0f;
    for (int t = 1; t < 1024; ++t) {
        float lt = lt_nxt;
        if (t < 1023) lt_nxt = (j < NTAG) ? lgt[(t + 1) * 16 + j] : 0.0f;
        float best = -3.0e38f; int arg = 0;
#pragma unroll
        for (int i = 0; i < NTAG; ++i) {
            float s = __shfl(v, i) + crfj[i];
            if (s > best) { best = s; arg = i; }   // strict > keeps lowest index (jnp.argmax)
        }
        v = (j < NTAG) ? (lt + best) : -3.0e38f;
        if (j < 16) bp[t][j] = (unsigned char)arg;
    }
    float best = -3.0e38f; int tag = 0;
#pragma unroll
    for (int jj = 0; jj < NTAG; ++jj) {
        float s = __shfl(v, jj);
        if (s > best) { best = s; tag = jj; }
    }
    __syncthreads();
    if (j == 0) {
        out[b] = best;
        int tg = tag;
        pth[1023] = (unsigned char)tg;
        for (int t = 1023; t >= 1; --t) {
            tg = bp[t][tg];
            pth[t - 1] = (unsigned char)tg;
        }
    }
    __syncthreads();
    float* pout = out + 32 + (size_t)b * 1024;
    for (int t = j; t < 1024; t += 64)
        pout[t] = (float)pth[t];
}

extern "C" void kernel_launch(void* const* d_in, const int* in_sizes, int n_in,
                              void* d_out, int out_size, void* d_ws, size_t ws_size,
                              hipStream_t stream) {
    const int* sent = (const int*)d_in[0];
    const float* emb = (const float*)d_in[1];
    const float* wih_f = (const float*)d_in[2];
    const float* whh_f = (const float*)d_in[3];
    const float* bih_f = (const float*)d_in[4];
    const float* bhh_f = (const float*)d_in[5];
    const float* wih_b = (const float*)d_in[6];
    const float* whh_b = (const float*)d_in[7];
    const float* bih_b = (const float*)d_in[8];
    const float* bhh_b = (const float*)d_in[9];
    const float* h0 = (const float*)d_in[10];
    const float* c0 = (const float*)d_in[11];
    const float* wout = (const float*)d_in[12];
    const float* b_out = (const float*)d_in[13];
    const float* crf = (const float*)d_in[14];

    char* ws = (char*)d_ws;
    signed char* qw       = (signed char*)(ws + 0);               // 512 KiB
    float* sw             = (float*)(ws + 524288);                // 8 KiB
    unsigned short* wih_bf = (unsigned short*)(ws + 1048576);     // 1 MiB
    float* biasc          = (float*)(ws + 2097152);               // 8 KiB
    unsigned short* wout_bf = (unsigned short*)(ws + 2105344);    // 16 KiB
    unsigned short* xbf   = (unsigned short*)(ws + 2121728);      // 16 MiB
    unsigned short* xg4   = (unsigned short*)(ws + 18898944);     // 128 MiB
    unsigned short* hs    = (unsigned short*)(ws + 153116672);    // 32 MiB
    float* logits         = (float*)(ws + 186671104);             // 2 MiB
    float* out = (float*)d_out;

    hipLaunchKernelGGL(prep_kernel, dim3(2088), dim3(256), 0, stream,
                       wih_f, wih_b, bih_f, bhh_f, bih_b, bhh_b, wout,
                       wih_bf, biasc, wout_bf);
    hipLaunchKernelGGL(wquant_kernel, dim3(512), dim3(256), 0, stream,
                       whh_f, whh_b, qw, sw);
    hipLaunchKernelGGL(embed_kernel, dim3(8192), dim3(256), 0, stream, sent, emb, xbf);
    hipLaunchKernelGGL(xproj_kernel, dim3(1024, 16), dim3(256), 0, stream,
                       xbf, wih_bf, biasc, xg4);
    hipLaunchKernelGGL(lstm_kernel, dim3(32), dim3(512), 0, stream,
                       xg4, qw, sw, h0, c0, hs);
    hipLaunchKernelGGL(logits_kernel, dim3(512), dim3(256), 0, stream,
                       hs, wout_bf, b_out, logits);
    hipLaunchKernelGGL(viterbi_kernel, dim3(32), dim3(64), 0, stream, logits, crf, out);
}

// Round 8
// 2041.972 us; speedup vs baseline: 2.2421x; 1.0285x over previous
//
#include <hip/hip_runtime.h>
#include <hip/hip_bf16.h>
#include <cstdint>

#define B_ 32
#define T_ 1024
#define E_ 256
#define H_ 256
#define G_ 1024
#define NTAG 14

typedef __bf16 bf8_t __attribute__((ext_vector_type(8)));
typedef float f4_t __attribute__((ext_vector_type(4)));
typedef int i4_t __attribute__((ext_vector_type(4)));
typedef unsigned short u16x4 __attribute__((ext_vector_type(4)));

__device__ __forceinline__ unsigned short f2bf(float f) {
    unsigned u = __builtin_bit_cast(unsigned, f);
    u = u + 0x7FFFu + ((u >> 16) & 1u);
    return (unsigned short)(u >> 16);
}
__device__ __forceinline__ float bf2f(unsigned short s) {
    unsigned u = ((unsigned)s) << 16;
    return __builtin_bit_cast(float, u);
}
__device__ __forceinline__ float sigf(float x) { return 1.0f / (1.0f + __expf(-x)); }
// branch-free tanh: overflow-safe (exp->inf => 1; exp->0 => -1)
__device__ __forceinline__ float tanh2_(float x) {
    float e = __expf(2.0f * x);
    return 1.0f - 2.0f / (e + 1.0f);
}
__device__ __forceinline__ f4_t mfma16(bf8_t a, bf8_t b, f4_t c) {
    return __builtin_amdgcn_mfma_f32_16x16x32_bf16(a, b, c, 0, 0, 0);
}
__device__ __forceinline__ int bperm(int srcl, int v) {
    return __builtin_amdgcn_ds_bpermute(srcl << 2, v);
}

// ---------------- prep: wih->bf16, combine biases, wout pad ----------------
__global__ __launch_bounds__(256) void prep_kernel(
        const float* wih_f, const float* wih_b,
        const float* bih_f, const float* bhh_f,
        const float* bih_b, const float* bhh_b,
        const float* wout,
        unsigned short* wih_bf, float* biasc, unsigned short* wout_bf) {
    int tid = blockIdx.x * 256 + threadIdx.x;
    if (tid < 524288) {                       // 2 x 262144: [d][1024][256]
        int d = tid >> 18, off = tid & 262143;
        wih_bf[tid] = f2bf((d ? wih_b : wih_f)[off]);
        return;
    }
    int t2 = tid - 524288;
    if (t2 < 8192) {                          // wout padded [16][512]
        int n = t2 >> 9, k = t2 & 511;
        wout_bf[t2] = (n < NTAG) ? f2bf(wout[n * 512 + k]) : (unsigned short)0;
        return;
    }
    int t3 = t2 - 8192;
    if (t3 < 2048) {                          // biasc [2][1024]
        int d = t3 >> 10, g = t3 & 1023;
        biasc[t3] = d ? (bih_b[g] + bhh_b[g]) : (bih_f[g] + bhh_f[g]);
    }
}

// ---------------- whh -> int8 with per-row scale ----------------
__global__ __launch_bounds__(256) void wquant_kernel(const float* whh_f, const float* whh_b,
                                                     signed char* qw, float* sw) {
    int row = blockIdx.x * 4 + (threadIdx.x >> 6);   // 0..2047 = [d][1024]
    int l = threadIdx.x & 63;
    int d = row >> 10, rr = row & 1023;
    const float* src = (d ? whh_b : whh_f) + (size_t)rr * 256;
    float4 v = *reinterpret_cast<const float4*>(src + 4 * l);
    float am = fmaxf(fmaxf(fabsf(v.x), fabsf(v.y)), fmaxf(fabsf(v.z), fabsf(v.w)));
#pragma unroll
    for (int off = 1; off < 64; off <<= 1)
        am = fmaxf(am, __shfl_xor(am, off));
    am = fmaxf(am, 1e-20f);
    float inv = 127.f / am;
    int q0 = (int)__builtin_rintf(v.x * inv), q1 = (int)__builtin_rintf(v.y * inv);
    int q2 = (int)__builtin_rintf(v.z * inv), q3 = (int)__builtin_rintf(v.w * inv);
    unsigned u = (q0 & 255) | ((q1 & 255) << 8) | ((q2 & 255) << 16) | ((q3 & 255) << 24);
    *reinterpret_cast<unsigned*>(qw + (size_t)row * 256 + 4 * l) = u;
    if (l == 0) sw[row] = am / 127.f;
}

// ---------------- embedding gather -> bf16 ----------------
__global__ __launch_bounds__(256) void embed_kernel(const int* sent, const float* emb,
                                                    unsigned short* xbf) {
    int tid = blockIdx.x * 256 + threadIdx.x; // 32768*64 threads
    int bt = tid >> 6;
    int e0 = (tid & 63) << 2;
    int tok = sent[bt];
    float4 v = *reinterpret_cast<const float4*>(emb + (size_t)tok * E_ + e0);
    u16x4 o;
    o[0] = f2bf(v.x); o[1] = f2bf(v.y); o[2] = f2bf(v.z); o[3] = f2bf(v.w);
    *reinterpret_cast<u16x4*>(xbf + (size_t)bt * E_ + e0) = o;
}

// ---- input projection -> xg4[d*16+b2][t][m 2][1024 n], coalesced via LDS transpose ----
__global__ __launch_bounds__(256) void xproj_kernel(const unsigned short* xbf,
        const unsigned short* wih_bf, const float* biasc, unsigned short* xg4) {
    int t = blockIdx.x;                  // 0..1023
    int y = blockIdx.y;                  // d*8 + bh*4 + ns
    int ns = y & 3, bh = (y >> 2) & 1, d = y >> 3;
    int w = threadIdx.x >> 6, l = threadIdx.x & 63;
    int l15 = l & 15, lgp = l >> 4;
    __shared__ unsigned short sh[256][16];

    bf8_t a[8];
    const unsigned short* arow = xbf + ((size_t)(16 * bh + l15) * 1024 + t) * E_ + 8 * lgp;
#pragma unroll
    for (int ks = 0; ks < 8; ++ks)
        a[ks] = *reinterpret_cast<const bf8_t*>(arow + 32 * ks);

    int nbase = ns * 256 + w * 64;
    const unsigned short* wd = wih_bf + (size_t)d * 262144;
    f4_t acc[4];
#pragma unroll
    for (int p = 0; p < 4; ++p) { acc[p][0] = 0.f; acc[p][1] = 0.f; acc[p][2] = 0.f; acc[p][3] = 0.f; }
#pragma unroll
    for (int p = 0; p < 4; ++p) {
        int n = nbase + 16 * p + l15;
        const unsigned short* brow = wd + (size_t)n * E_ + 8 * lgp;
#pragma unroll
        for (int ks = 0; ks < 8; ++ks) {
            bf8_t b = *reinterpret_cast<const bf8_t*>(brow + 32 * ks);
            acc[p] = mfma16(a[ks], b, acc[p]);
        }
    }
#pragma unroll
    for (int p = 0; p < 4; ++p) {
        int n = nbase + 16 * p + l15;
        float bias = biasc[d * G_ + n];
#pragma unroll
        for (int r = 0; r < 4; ++r)
            sh[w * 64 + 16 * p + l15][4 * lgp + r] = f2bf(acc[p][r] + bias);
    }
    __syncthreads();
    // writeout: thread q owns n = ns*256+q; 16 coalesced scalar stores
    int q = threadIdx.x;
#pragma unroll
    for (int p = 0; p < 8; ++p) {
        int b2g = 8 * bh + p;
        size_t base = ((size_t)(d * 16 + b2g) * 1024 + t) * 2048 + ns * 256 + q;
        xg4[base]        = sh[q][2 * p];      // m=0
        xg4[base + 1024] = sh[q][2 * p + 1];  // m=1
    }
}

// ------- recurrence: 32 WGs = (dir, batch-pair); 1 barrier/step, bpermute epilogue ----
__global__ __launch_bounds__(512, 2) void lstm_kernel(const unsigned short* xg4,
        const signed char* qw, const float* sw, const float* h0, const float* c0,
        unsigned short* hs) {
    int bid = blockIdx.x;            // 0..31
    int b2 = bid & 15, d = bid >> 4;
    int tid = threadIdx.x;
    int w = tid >> 6, l = tid & 63, l15 = l & 15, lgp = l >> 4;

    __shared__ __attribute__((aligned(16))) signed char h8[2][2][320]; // parity x m x col
    __shared__ i4_t wsh[4096];       // 64 KiB: ks=3 weight quarter
    __shared__ float red_sh[8];

    const signed char* qwd = qw + (size_t)d * 262144;

    // ks 0..2 weights -> registers (24 quads = 96 VGPR)
    i4_t wreg[4][2][3];
#pragma unroll
    for (int gt = 0; gt < 4; ++gt)
#pragma unroll
        for (int jt = 0; jt < 2; ++jt) {
            int n = 256 * gt + 32 * w + 16 * jt + l15;
#pragma unroll
            for (int ks = 0; ks < 3; ++ks)
                wreg[gt][jt][ks] = *reinterpret_cast<const i4_t*>(
                    qwd + (size_t)n * 256 + 64 * ks + 16 * lgp);
        }
#pragma unroll
    for (int gt = 0; gt < 4; ++gt)
#pragma unroll
        for (int jt = 0; jt < 2; ++jt)
#pragma unroll
            for (int ks = 0; ks < 3; ++ks)
                asm volatile("" : "+v"(wreg[gt][jt][ks]));   // keep resident

    // ks=3 weights -> LDS
#pragma unroll
    for (int gt = 0; gt < 4; ++gt)
#pragma unroll
        for (int jt = 0; jt < 2; ++jt) {
            int n = 256 * gt + 32 * w + 16 * jt + l15;
            wsh[(w * 8 + gt * 2 + jt) * 64 + l] = *reinterpret_cast<const i4_t*>(
                qwd + (size_t)n * 256 + 192 + 16 * lgp);
        }

    // ---- cell coords: one cell per lane, wave-local ----
    int jl = l & 31;          // local j within wave's 32 cols
    int m  = l >> 5;          // batch row within pair
    int j  = 32 * w + jl;     // global h column
    int jt_c = (jl >> 4) & 1; // source jt
    int srcl = jl & 15;       // source act lane (lgp==0)

    float swv[4];
#pragma unroll
    for (int gt = 0; gt < 4; ++gt)
        swv[gt] = sw[d * 1024 + 256 * gt + j];
    float c = c0[((size_t)d * 32 + b2 * 2 + m) * 256 + j];

    // h0: block amax -> step-0 scale, quantize into parity-1
    float v0 = h0[((size_t)d * 32 + b2 * 2 + m) * 256 + j];
    float am = fabsf(v0);
#pragma unroll
    for (int off = 1; off < 64; off <<= 1)
        am = fmaxf(am, __shfl_xor(am, off));
    if (l == 0) red_sh[w] = am;
    __syncthreads();
    float bmax = red_sh[0];
#pragma unroll
    for (int q = 1; q < 8; ++q) bmax = fmaxf(bmax, red_sh[q]);
    bmax = fmaxf(bmax, 1e-20f);
    float s0 = bmax / 127.f;
    h8[1][m][j] = (signed char)(int)__builtin_rintf(v0 * (127.f / bmax));

    float dq[4];
#pragma unroll
    for (int gt = 0; gt < 4; ++gt) dq[gt] = swv[gt] * s0;

    // ---- streaming pointers (t is monotone) ----
    int t0 = d ? 1023 : 0;
    int xinc = d ? -2048 : 2048;
    int hinc = d ? -512 : 512;
    const unsigned short* xq = xg4 + ((size_t)(d * 16 + b2) * 1024 + t0) * 2048
                               + m * 1024 + j;
    unsigned short* hsp = hs + ((size_t)(b2 * 2 + m) * 1024 + t0) * 512 + d * 256 + j;

    unsigned short xc[4], xn[4];
#pragma unroll
    for (int gt = 0; gt < 4; ++gt) xc[gt] = xq[256 * gt];

    i4_t z4 = (i4_t){0, 0, 0, 0};
    asm volatile("" : "+v"(z4));   // persistent zero C-operand

    __syncthreads();   // weights staged + h(-1) ready

    for (int s = 0; s < 1024; ++s) {
        int rp = (s + 1) & 1, wp = s & 1;

        // prefetch next step's xg values (full step of latency cover)
        if (s < 1023) {
            xq += xinc;
#pragma unroll
            for (int gt = 0; gt < 4; ++gt) xn[gt] = xq[256 * gt];
        }

        // A fragments (rows 0,1 broadcast-duplicated across 16 A-rows)
        i4_t a[4];
#pragma unroll
        for (int ks = 0; ks < 4; ++ks)
            a[ks] = *reinterpret_cast<const i4_t*>(&h8[rp][l15 & 1][64 * ks + 16 * lgp]);

        i4_t acc[4][2];
#pragma unroll
        for (int gt = 0; gt < 4; ++gt)
#pragma unroll
            for (int jt = 0; jt < 2; ++jt) {
                acc[gt][jt] = __builtin_amdgcn_mfma_i32_16x16x64_i8(
                    a[0], wreg[gt][jt][0], z4, 0, 0, 0);
#pragma unroll
                for (int ks = 1; ks < 3; ++ks)
                    acc[gt][jt] = __builtin_amdgcn_mfma_i32_16x16x64_i8(
                        a[ks], wreg[gt][jt][ks], acc[gt][jt], 0, 0, 0);
                i4_t b = wsh[(w * 8 + gt * 2 + jt) * 64 + l];
                acc[gt][jt] = __builtin_amdgcn_mfma_i32_16x16x64_i8(
                    a[3], b, acc[gt][jt], 0, 0, 0);
            }

        // wave-local redistribute: pull this cell's 4 gate ints from act lanes
        int gi[4];
#pragma unroll
        for (int gt = 0; gt < 4; ++gt) {
            int p00 = bperm(srcl, acc[gt][0][0]);
            int p01 = bperm(srcl, acc[gt][0][1]);
            int p10 = bperm(srcl, acc[gt][1][0]);
            int p11 = bperm(srcl, acc[gt][1][1]);
            int t0v = jt_c ? p10 : p00;
            int t1v = jt_c ? p11 : p01;
            gi[gt] = m ? t1v : t0v;
        }

        // epilogue: every lane computes its one cell
        float pi = dq[0] * (float)gi[0] + bf2f(xc[0]);
        float pf = dq[1] * (float)gi[1] + bf2f(xc[1]);
        float pg = dq[2] * (float)gi[2] + bf2f(xc[2]);
        float po = dq[3] * (float)gi[3] + bf2f(xc[3]);
        float iv = sigf(pi), fv = sigf(pf), ov = sigf(po);
        float gv = tanh2_(pg);
        float cn = fv * c + iv * gv;
        c = cn;
        float hv = ov * tanh2_(cn);
        *hsp = f2bf(hv);
        hsp += hinc;
        h8[wp][m][j] = (signed char)(int)__builtin_rintf(hv * 127.f);

        if (s == 0) {
#pragma unroll
            for (int gt = 0; gt < 4; ++gt) dq[gt] = swv[gt] * (1.f / 127.f);
        }
#pragma unroll
        for (int gt = 0; gt < 4; ++gt) xc[gt] = xn[gt];

        // single barrier: h8[wp] complete for next step (LDS drain only)
        asm volatile("s_waitcnt lgkmcnt(0)" ::: "memory");
        __builtin_amdgcn_sched_barrier(0);
        __builtin_amdgcn_s_barrier();
    }
}

// ---------------- logits = hs @ Wout^T + b_out (N padded to 16) ----------------
__global__ __launch_bounds__(256) void logits_kernel(const unsigned short* hs,
        const unsigned short* wout_bf, const float* b_out, float* logits) {
    int w = threadIdx.x >> 6, l = threadIdx.x & 63, l15 = l & 15, lgp = l >> 4;
    int mt = blockIdx.x * 4 + w;         // 0..2047
    const unsigned short* arow = hs + (size_t)(16 * mt + l15) * 512 + 8 * lgp;
    const unsigned short* brow = wout_bf + (size_t)l15 * 512 + 8 * lgp;
    f4_t acc; acc[0] = 0.f; acc[1] = 0.f; acc[2] = 0.f; acc[3] = 0.f;
#pragma unroll
    for (int ks = 0; ks < 16; ++ks) {
        bf8_t a = *reinterpret_cast<const bf8_t*>(arow + 32 * ks);
        bf8_t b = *reinterpret_cast<const bf8_t*>(brow + 32 * ks);
        acc = mfma16(a, b, acc);
    }
    float bo = (l15 < NTAG) ? b_out[l15] : 0.0f;
#pragma unroll
    for (int r = 0; r < 4; ++r) {
        int bt = 16 * mt + 4 * lgp + r;
        logits[(size_t)bt * 16 + l15] = acc[r] + bo;
    }
}

// ---------------- Viterbi: one wave per sequence; tree argmax ----------------
__global__ __launch_bounds__(64) void viterbi_kernel(const float* logits, const float* crf,
                                                     float* out) {
    int b = blockIdx.x, j = threadIdx.x;
    __shared__ unsigned char bp[1024][16];
    __shared__ unsigned char pth[1024];
    float crfj[NTAG];
#pragma unroll
    for (int i = 0; i < NTAG; ++i)
        crfj[i] = (j < NTAG) ? crf[i * NTAG + j] : 0.0f;
    const float* lgt = logits + (size_t)b * 1024 * 16;
    float v = (j < NTAG) ? lgt[j] : -3.0e38f;
    float lt_nxt = (j < NTAG) ? lgt[16 + j] : 0.0f;
    for (int t = 1; t < 1024; ++t) {
        float lt = lt_nxt;
        if (t < 1023) lt_nxt = (j < NTAG) ? lgt[(t + 1) * 16 + j] : 0.0f;
        // gather candidates (independent shfl; ILP)
        float sv[NTAG];
#pragma unroll
        for (int i = 0; i < NTAG; ++i)
            sv[i] = __shfl(v, i) + crfj[i];
        // tree argmax (lowest index wins on ties: take right only if strictly >)
        float av[7]; int ai[7];
#pragma unroll
        for (int i = 0; i < 7; ++i) {
            bool rgt = sv[2 * i + 1] > sv[2 * i];
            av[i] = rgt ? sv[2 * i + 1] : sv[2 * i];
            ai[i] = rgt ? 2 * i + 1 : 2 * i;
        }
        float bv[4]; int bi[4];
#pragma unroll
        for (int i = 0; i < 3; ++i) {
            bool rgt = av[2 * i + 1] > av[2 * i];
            bv[i] = rgt ? av[2 * i + 1] : av[2 * i];
            bi[i] = rgt ? ai[2 * i + 1] : ai[2 * i];
        }
        bv[3] = av[6]; bi[3] = ai[6];
        float cv0 = (bv[1] > bv[0]) ? bv[1] : bv[0];
        int   ci0 = (bv[1] > bv[0]) ? bi[1] : bi[0];
        float cv1 = (bv[3] > bv[2]) ? bv[3] : bv[2];
        int   ci1 = (bv[3] > bv[2]) ? bi[3] : bi[2];
        float best = (cv1 > cv0) ? cv1 : cv0;
        int   arg  = (cv1 > cv0) ? ci1 : ci0;
        v = (j < NTAG) ? (lt + best) : -3.0e38f;
        if (j < 16) bp[t][j] = (unsigned char)arg;
    }
    float best = -3.0e38f; int tag = 0;
#pragma unroll
    for (int jj = 0; jj < NTAG; ++jj) {
        float s = __shfl(v, jj);
        if (s > best) { best = s; tag = jj; }
    }
    __syncthreads();
    if (j == 0) {
        out[b] = best;
        int tg = tag;
        pth[1023] = (unsigned char)tg;
        for (int t = 1023; t >= 1; --t) {
            tg = bp[t][tg];
            pth[t - 1] = (unsigned char)tg;
        }
    }
    __syncthreads();
    float* pout = out + 32 + (size_t)b * 1024;
    for (int t = j; t < 1024; t += 64)
        pout[t] = (float)pth[t];
}

extern "C" void kernel_launch(void* const* d_in, const int* in_sizes, int n_in,
                              void* d_out, int out_size, void* d_ws, size_t ws_size,
                              hipStream_t stream) {
    const int* sent = (const int*)d_in[0];
    const float* emb = (const float*)d_in[1];
    const float* wih_f = (const float*)d_in[2];
    const float* whh_f = (const float*)d_in[3];
    const float* bih_f = (const float*)d_in[4];
    const float* bhh_f = (const float*)d_in[5];
    const float* wih_b = (const float*)d_in[6];
    const float* whh_b = (const float*)d_in[7];
    const float* bih_b = (const float*)d_in[8];
    const float* bhh_b = (const float*)d_in[9];
    const float* h0 = (const float*)d_in[10];
    const float* c0 = (const float*)d_in[11];
    const float* wout = (const float*)d_in[12];
    const float* b_out = (const float*)d_in[13];
    const float* crf = (const float*)d_in[14];

    char* ws = (char*)d_ws;
    signed char* qw       = (signed char*)(ws + 0);               // 512 KiB
    float* sw             = (float*)(ws + 524288);                // 8 KiB
    unsigned short* wih_bf = (unsigned short*)(ws + 1048576);     // 1 MiB
    float* biasc          = (float*)(ws + 2097152);               // 8 KiB
    unsigned short* wout_bf = (unsigned short*)(ws + 2105344);    // 16 KiB
    unsigned short* xbf   = (unsigned short*)(ws + 2121728);      // 16 MiB
    unsigned short* xg4   = (unsigned short*)(ws + 18898944);     // 128 MiB
    unsigned short* hs    = (unsigned short*)(ws + 153116672);    // 32 MiB
    float* logits         = (float*)(ws + 186671104);             // 2 MiB
    float* out = (float*)d_out;

    hipLaunchKernelGGL(prep_kernel, dim3(2088), dim3(256), 0, stream,
                       wih_f, wih_b, bih_f, bhh_f, bih_b, bhh_b, wout,
                       wih_bf, biasc, wout_bf);
    hipLaunchKernelGGL(wquant_kernel, dim3(512), dim3(256), 0, stream,
                       whh_f, whh_b, qw, sw);
    hipLaunchKernelGGL(embed_kernel, dim3(8192), dim3(256), 0, stream, sent, emb, xbf);
    hipLaunchKernelGGL(xproj_kernel, dim3(1024, 16), dim3(256), 0, stream,
                       xbf, wih_bf, biasc, xg4);
    hipLaunchKernelGGL(lstm_kernel, dim3(32), dim3(512), 0, stream,
                       xg4, qw, sw, h0, c0, hs);
    hipLaunchKernelGGL(logits_kernel, dim3(512), dim3(256), 0, stream,
                       hs, wout_bf, b_out, logits);
    hipLaunchKernelGGL(viterbi_kernel, dim3(32), dim3(64), 0, stream, logits, crf, out);
}